// Round 1
// baseline (1925.552 us; speedup 1.0000x reference)
//
#include <hip/hip_runtime.h>
#include <float.h>
#include <math.h>

// Problem constants (from reference setup_inputs)
#define B_   32
#define D_   128
#define T_   2048
#define K_   2048
#define N_   (B_ * T_)      // 65536

#define BD   16             // d-tile depth for argmin GEMM

// ---------------------------------------------------------------------------
// Zero scratch accumulators (harness re-poisons ws with 0xAA every launch)
// ---------------------------------------------------------------------------
__global__ void zero_kernel(float* __restrict__ p, int n) {
    int i = blockIdx.x * 256 + threadIdx.x;
    if (i < n) p[i] = 0.0f;
}

// ---------------------------------------------------------------------------
// halfnorm[k] = 0.5 * ||e_k||^2   (one wave per code)
// ---------------------------------------------------------------------------
__global__ void halfnorm_kernel(const float* __restrict__ emb, float* __restrict__ hn) {
    int k = blockIdx.x;
    int l = threadIdx.x;            // 64 threads = 1 wave
    float a = emb[(size_t)k * D_ + l];
    float b = emb[(size_t)k * D_ + 64 + l];
    float s = a * a + b * b;
#pragma unroll
    for (int off = 32; off > 0; off >>= 1) s += __shfl_down(s, off, 64);
    if (l == 0) hn[k] = 0.5f * s;
}

// ---------------------------------------------------------------------------
// Distance argmin: per row n, idx[n] = argmin_k (0.5*||e_k||^2 - z_n . e_k)
// Tiled fp32 "GEMM": block = 128 rows x 128 codes, 256 threads, 8x8 micro-tile.
// z is [B, D, T]; row n = b*T + t reads z[b*D*T + d*T + t] (coalesced over t).
// ---------------------------------------------------------------------------
__global__ __launch_bounds__(256)
void argmin_kernel(const float* __restrict__ z, const float* __restrict__ emb,
                   const float* __restrict__ hn, int* __restrict__ idx) {
    __shared__ float As[BD][128];       // z tile   (d-major)  8 KB
    __shared__ float Bs[BD][128];       // code tile (d-major) 8 KB
    __shared__ float redv[128][16];     // argmin reduce       8 KB
    __shared__ int   redi[128][16];     //                     8 KB

    const int tid = threadIdx.x;
    const int tx = tid & 15;            // code group
    const int ty = tid >> 4;            // row group
    const int n0 = blockIdx.x * 128;    // 512 blocks; 128 rows stay within one b
    const int b  = n0 >> 11;            // T = 2048
    const int t0 = n0 & (T_ - 1);
    const float* zb = z + (size_t)b * D_ * T_ + t0;

    float minv[8];
    int   mini[8];
#pragma unroll
    for (int i = 0; i < 8; i++) { minv[i] = FLT_MAX; mini[i] = 0; }

    const int a_di = tid >> 5;          // 0..7 (+8 on second pass)
    const int a_r  = (tid & 31) << 2;   // 0..124

    for (int k0 = 0; k0 < K_; k0 += 128) {
        float acc[8][8];
#pragma unroll
        for (int i = 0; i < 8; i++)
#pragma unroll
            for (int j = 0; j < 8; j++) acc[i][j] = 0.0f;

        for (int d0 = 0; d0 < D_; d0 += BD) {
            __syncthreads();
            // stage z tile: 128 rows x 16 d, float4 coalesced along t
#pragma unroll
            for (int p = 0; p < 2; p++) {
                int di = a_di + p * 8;
                float4 av = *(const float4*)(zb + (size_t)(d0 + di) * T_ + a_r);
                *(float4*)&As[di][a_r] = av;
            }
            // stage code tile: 128 codes x 16 d, float4 along d, transposed store
#pragma unroll
            for (int p = 0; p < 2; p++) {
                int c  = p * 256 + tid;
                int kk = c >> 2;
                int dq = c & 3;
                float4 bv = *(const float4*)(emb + (size_t)(k0 + kk) * D_ + d0 + dq * 4);
                Bs[dq * 4 + 0][kk] = bv.x;
                Bs[dq * 4 + 1][kk] = bv.y;
                Bs[dq * 4 + 2][kk] = bv.z;
                Bs[dq * 4 + 3][kk] = bv.w;
            }
            __syncthreads();
#pragma unroll
            for (int d = 0; d < BD; d++) {
                float4 a0 = *(const float4*)&As[d][ty * 4];
                float4 a1 = *(const float4*)&As[d][64 + ty * 4];
                float4 b0 = *(const float4*)&Bs[d][tx * 4];
                float4 b1 = *(const float4*)&Bs[d][64 + tx * 4];
                float a_[8] = {a0.x, a0.y, a0.z, a0.w, a1.x, a1.y, a1.z, a1.w};
                float b_[8] = {b0.x, b0.y, b0.z, b0.w, b1.x, b1.y, b1.z, b1.w};
#pragma unroll
                for (int i = 0; i < 8; i++)
#pragma unroll
                    for (int j = 0; j < 8; j++)
                        acc[i][j] += a_[i] * b_[j];
            }
        }
        // epilogue for this K-tile: score = halfnorm - dot; running argmin.
        // codes visited in ascending order within a thread -> strict < keeps first min.
#pragma unroll
        for (int j = 0; j < 8; j++) {
            int kidx = k0 + ((j < 4) ? (tx * 4 + j) : (64 + tx * 4 + (j - 4)));
            float h = hn[kidx];
#pragma unroll
            for (int i = 0; i < 8; i++) {
                float s = h - acc[i][j];
                if (s < minv[i]) { minv[i] = s; mini[i] = kidx; }
            }
        }
    }

    __syncthreads();
#pragma unroll
    for (int i = 0; i < 8; i++) {
        int r = (i < 4) ? (ty * 4 + i) : (64 + ty * 4 + (i - 4));
        redv[r][tx] = minv[i];
        redi[r][tx] = mini[i];
    }
    __syncthreads();
    if (tid < 128) {
        float bv = redv[tid][0];
        int   bi = redi[tid][0];
#pragma unroll
        for (int x = 1; x < 16; x++) {
            float v  = redv[tid][x];
            int   id = redi[tid][x];
            if (v < bv || (v == bv && id < bi)) { bv = v; bi = id; }
        }
        idx[n0 + tid] = bi;
    }
}

// ---------------------------------------------------------------------------
// Gather z_vq, write STE output, accumulate loss, segment sums (atomics)
// ---------------------------------------------------------------------------
__global__ __launch_bounds__(256)
void scatter_kernel(const float* __restrict__ z, const float* __restrict__ emb,
                    const int* __restrict__ idx, float* __restrict__ out0,
                    float* __restrict__ sum_new, float* __restrict__ elem_new,
                    float* __restrict__ s_loss) {
    const int tid = threadIdx.x;
    const int blk = blockIdx.x;               // 256 blocks
    const int t   = (blk & 7) * 256 + tid;    // t within batch
    const int b   = blk >> 3;
    const int n   = b * T_ + t;
    const int code = idx[n];

    const float* zp = z    + (size_t)b * D_ * T_ + t;
    float*       op = out0 + (size_t)b * D_ * T_ + t;
    const float* ep = emb     + (size_t)code * D_;
    float*       sp = sum_new + (size_t)code * D_;

    float lsum = 0.0f;
    for (int d = 0; d < D_; d++) {
        float zv = zp[(size_t)d * T_];
        float ev = ep[d];
        float df = ev - zv;                 // z_vq - zf (one rounding)
        op[(size_t)d * T_] = zv + df;       // zf + (z_vq - zf), matches reference STE
        lsum += df * df;
        atomicAdd(&sp[d], zv);
    }
    atomicAdd(&elem_new[code], 1.0f);

    __shared__ float red[256];
    red[tid] = lsum;
    __syncthreads();
    for (int s = 128; s > 0; s >>= 1) {
        if (tid < s) red[tid] += red[tid + s];
        __syncthreads();
    }
    if (tid == 0) atomicAdd(s_loss, red[0]);
}

// ---------------------------------------------------------------------------
// EMA update, emb_new select, dk / entropy partial sums
// ---------------------------------------------------------------------------
__global__ __launch_bounds__(256)
void update_kernel(const float* __restrict__ emb, const float* __restrict__ emb_sum,
                   const float* __restrict__ emb_elem, const float* __restrict__ emb_rand,
                   const float* __restrict__ sum_new, const float* __restrict__ elem_new,
                   float* __restrict__ out_emb_new, float* __restrict__ out_emb_sum_n,
                   float* __restrict__ out_emb_elem_n,
                   float* __restrict__ s_ent, float* __restrict__ s_dk) {
    const float MU  = 0.99f;
    const float OMM = (float)(1.0 - 0.99);   // match JAX's fp64 1.0-0.99 -> fp32
    int gid = blockIdx.x * 256 + threadIdx.x;   // < K_*D_ = 262144
    int k = gid >> 7;
    int d = gid & 127;

    float sn = sum_new[gid];
    float es = emb_sum[gid];
    float en = elem_new[k];
    float ee = emb_elem[k];
    float esn = MU * es + OMM * sn;
    float een = MU * ee + OMM * en;
    out_emb_sum_n[gid] = esn;
    float enew = (een >= 1.0f) ? (esn / een) : emb_rand[gid];
    out_emb_new[gid] = enew;

    float df = enew - emb[gid];
    float v  = df * df;
    __shared__ float red[256];
    red[threadIdx.x] = v;
    __syncthreads();
    for (int s = 128; s > 0; s >>= 1) {
        if (threadIdx.x < s) red[threadIdx.x] += red[threadIdx.x + s];
        __syncthreads();
    }
    if (threadIdx.x == 0) atomicAdd(s_dk, red[0]);

    if (d == 0) {
        out_emb_elem_n[k] = een;
        float p = en * (1.0f / 65536.0f);   // sum(elem_new) == N exactly in fp32
        atomicAdd(s_ent, p * logf(p + 1e-8f));
    }
}

// ---------------------------------------------------------------------------
// Scalar finalization
// ---------------------------------------------------------------------------
__global__ void final_kernel(const float* __restrict__ s_loss, const float* __restrict__ s_ent,
                             const float* __restrict__ s_dk,
                             float* __restrict__ out_loss, float* __restrict__ out_ent,
                             float* __restrict__ out_dk) {
    out_loss[0] = s_loss[0];
    out_ent[0]  = expf(-s_ent[0]);
    out_dk[0]   = sqrtf(s_dk[0]) * (1.0f / 512.0f);   // sqrt(K*D) = 512
}

// ---------------------------------------------------------------------------
extern "C" void kernel_launch(void* const* d_in, const int* in_sizes, int n_in,
                              void* d_out, int out_size, void* d_ws, size_t ws_size,
                              hipStream_t stream) {
    (void)in_sizes; (void)n_in; (void)out_size; (void)ws_size;

    const float* z        = (const float*)d_in[0];   // [32,128,2048]
    const float* emb      = (const float*)d_in[1];   // [2048,128]
    const float* emb_sum  = (const float*)d_in[2];   // [2048,128]
    const float* emb_elem = (const float*)d_in[3];   // [2048]
    const float* emb_rand = (const float*)d_in[4];   // [2048,128]

    float* out = (float*)d_out;
    float* out0            = out;                            // z_vq_out  8388608
    float* out_loss        = out + 8388608;                  // scalar
    float* out_emb_new     = out + 8388609;                  // 262144
    float* out_emb_sum_n   = out + 8388609 + 262144;         // 262144
    float* out_emb_elem_n  = out + 8388609 + 524288;         // 2048
    float* out_ent         = out + 8388609 + 524288 + 2048;  // scalar
    float* out_dk          = out_ent + 1;                    // scalar

    float* ws       = (float*)d_ws;
    int*   idx      = (int*)ws;          // 65536 ints
    float* hn       = ws + 65536;        // 2048
    float* sum_new  = ws + 67584;        // 262144
    float* elem_new = ws + 329728;       // 2048
    float* s_loss   = ws + 331776;
    float* s_ent    = ws + 331777;
    float* s_dk     = ws + 331778;

    const int zero_n = 262144 + 2048 + 3;   // sum_new .. s_dk contiguous
    zero_kernel<<<(zero_n + 255) / 256, 256, 0, stream>>>(sum_new, zero_n);
    halfnorm_kernel<<<K_, 64, 0, stream>>>(emb, hn);
    argmin_kernel<<<N_ / 128, 256, 0, stream>>>(z, emb, hn, idx);
    scatter_kernel<<<N_ / 256, 256, 0, stream>>>(z, emb, idx, out0, sum_new, elem_new, s_loss);
    update_kernel<<<(K_ * D_) / 256, 256, 0, stream>>>(emb, emb_sum, emb_elem, emb_rand,
                                                       sum_new, elem_new,
                                                       out_emb_new, out_emb_sum_n,
                                                       out_emb_elem_n, s_ent, s_dk);
    final_kernel<<<1, 1, 0, stream>>>(s_loss, s_ent, s_dk, out_loss, out_ent, out_dk);
}

// Round 2
// 1119.904 us; speedup vs baseline: 1.7194x; 1.7194x over previous
//
#include <hip/hip_runtime.h>
#include <float.h>
#include <math.h>

// Problem constants (from reference setup_inputs)
#define B_   32
#define D_   128
#define T_   2048
#define K_   2048
#define N_   (B_ * T_)      // 65536

#define BD   16             // d-tile depth for argmin GEMM

// ---------------------------------------------------------------------------
// Zero scratch accumulators (harness re-poisons ws with 0xAA every launch)
// ---------------------------------------------------------------------------
__global__ void zero_kernel(float* __restrict__ p, int n) {
    int i = blockIdx.x * 256 + threadIdx.x;
    if (i < n) p[i] = 0.0f;
}

// ---------------------------------------------------------------------------
// halfnorm[k] = 0.5 * ||e_k||^2   (one wave per code)
// ---------------------------------------------------------------------------
__global__ void halfnorm_kernel(const float* __restrict__ emb, float* __restrict__ hn) {
    int k = blockIdx.x;
    int l = threadIdx.x;            // 64 threads = 1 wave
    float a = emb[(size_t)k * D_ + l];
    float b = emb[(size_t)k * D_ + 64 + l];
    float s = a * a + b * b;
#pragma unroll
    for (int off = 32; off > 0; off >>= 1) s += __shfl_down(s, off, 64);
    if (l == 0) hn[k] = 0.5f * s;
}

// ---------------------------------------------------------------------------
// Distance argmin: per row n, idx[n] = argmin_k (0.5*||e_k||^2 - z_n . e_k)
// Tiled fp32 "GEMM": block = 128 rows x 128 codes, 256 threads, 8x8 micro-tile.
// z is [B, D, T]; row n = b*T + t reads z[b*D*T + d*T + t] (coalesced over t).
// ---------------------------------------------------------------------------
__global__ __launch_bounds__(256)
void argmin_kernel(const float* __restrict__ z, const float* __restrict__ emb,
                   const float* __restrict__ hn, int* __restrict__ idx) {
    __shared__ float As[BD][128];       // z tile   (d-major)  8 KB
    __shared__ float Bs[BD][128];       // code tile (d-major) 8 KB
    __shared__ float redv[128][16];     // argmin reduce       8 KB
    __shared__ int   redi[128][16];     //                     8 KB

    const int tid = threadIdx.x;
    const int tx = tid & 15;            // code group
    const int ty = tid >> 4;            // row group
    const int n0 = blockIdx.x * 128;    // 512 blocks; 128 rows stay within one b
    const int b  = n0 >> 11;            // T = 2048
    const int t0 = n0 & (T_ - 1);
    const float* zb = z + (size_t)b * D_ * T_ + t0;

    float minv[8];
    int   mini[8];
#pragma unroll
    for (int i = 0; i < 8; i++) { minv[i] = FLT_MAX; mini[i] = 0; }

    const int a_di = tid >> 5;          // 0..7 (+8 on second pass)
    const int a_r  = (tid & 31) << 2;   // 0..124

    for (int k0 = 0; k0 < K_; k0 += 128) {
        float acc[8][8];
#pragma unroll
        for (int i = 0; i < 8; i++)
#pragma unroll
            for (int j = 0; j < 8; j++) acc[i][j] = 0.0f;

        for (int d0 = 0; d0 < D_; d0 += BD) {
            __syncthreads();
            // stage z tile: 128 rows x 16 d, float4 coalesced along t
#pragma unroll
            for (int p = 0; p < 2; p++) {
                int di = a_di + p * 8;
                float4 av = *(const float4*)(zb + (size_t)(d0 + di) * T_ + a_r);
                *(float4*)&As[di][a_r] = av;
            }
            // stage code tile: 128 codes x 16 d, float4 along d, transposed store
#pragma unroll
            for (int p = 0; p < 2; p++) {
                int c  = p * 256 + tid;
                int kk = c >> 2;
                int dq = c & 3;
                float4 bv = *(const float4*)(emb + (size_t)(k0 + kk) * D_ + d0 + dq * 4);
                Bs[dq * 4 + 0][kk] = bv.x;
                Bs[dq * 4 + 1][kk] = bv.y;
                Bs[dq * 4 + 2][kk] = bv.z;
                Bs[dq * 4 + 3][kk] = bv.w;
            }
            __syncthreads();
#pragma unroll
            for (int d = 0; d < BD; d++) {
                float4 a0 = *(const float4*)&As[d][ty * 4];
                float4 a1 = *(const float4*)&As[d][64 + ty * 4];
                float4 b0 = *(const float4*)&Bs[d][tx * 4];
                float4 b1 = *(const float4*)&Bs[d][64 + tx * 4];
                float a_[8] = {a0.x, a0.y, a0.z, a0.w, a1.x, a1.y, a1.z, a1.w};
                float b_[8] = {b0.x, b0.y, b0.z, b0.w, b1.x, b1.y, b1.z, b1.w};
#pragma unroll
                for (int i = 0; i < 8; i++)
#pragma unroll
                    for (int j = 0; j < 8; j++)
                        acc[i][j] += a_[i] * b_[j];
            }
        }
        // epilogue for this K-tile: score = halfnorm - dot; running argmin.
        // codes visited in ascending order within a thread -> strict < keeps first min.
#pragma unroll
        for (int j = 0; j < 8; j++) {
            int kidx = k0 + ((j < 4) ? (tx * 4 + j) : (64 + tx * 4 + (j - 4)));
            float h = hn[kidx];
#pragma unroll
            for (int i = 0; i < 8; i++) {
                float s = h - acc[i][j];
                if (s < minv[i]) { minv[i] = s; mini[i] = kidx; }
            }
        }
    }

    __syncthreads();
#pragma unroll
    for (int i = 0; i < 8; i++) {
        int r = (i < 4) ? (ty * 4 + i) : (64 + ty * 4 + (i - 4));
        redv[r][tx] = minv[i];
        redi[r][tx] = mini[i];
    }
    __syncthreads();
    if (tid < 128) {
        float bv = redv[tid][0];
        int   bi = redi[tid][0];
#pragma unroll
        for (int x = 1; x < 16; x++) {
            float v  = redv[tid][x];
            int   id = redi[tid][x];
            if (v < bv || (v == bv && id < bi)) { bv = v; bi = id; }
        }
        idx[n0 + tid] = bi;
    }
}

// ---------------------------------------------------------------------------
// STE output + loss: block = 64 t x 128 d tile of one b. Coalesced float4
// read/write of z/out0; codebook gather is L2-resident (emb = 1 MB).
// ---------------------------------------------------------------------------
__global__ __launch_bounds__(256)
void ste_kernel(const float* __restrict__ z, const float* __restrict__ emb,
                const int* __restrict__ idx, float* __restrict__ out0,
                float* __restrict__ s_loss) {
    __shared__ int   scode[64];
    __shared__ float red[256];
    const int tid = threadIdx.x;
    const int blk = blockIdx.x;              // 1024 blocks
    const int b   = blk >> 5;
    const int t0  = (blk & 31) * 64;
    const int n0  = b * T_ + t0;
    if (tid < 64) scode[tid] = idx[n0 + tid];
    __syncthreads();

    const float* zb = z    + (size_t)b * D_ * T_ + t0;
    float*       ob = out0 + (size_t)b * D_ * T_ + t0;
    float lsum = 0.0f;
#pragma unroll
    for (int it = 0; it < 8; it++) {
        int flat = it * 256 + tid;           // 0..2047 covers 128 d x 16 q
        int d = flat >> 4;
        int q = flat & 15;
        float4 zv = *(const float4*)(zb + (size_t)d * T_ + q * 4);
        float zi[4] = {zv.x, zv.y, zv.z, zv.w};
        float ov[4];
#pragma unroll
        for (int j = 0; j < 4; j++) {
            int code = scode[q * 4 + j];
            float e  = emb[(size_t)code * D_ + d];
            float df = e - zi[j];            // z_vq - zf (one rounding)
            ov[j] = zi[j] + df;              // zf + (z_vq - zf), matches reference STE
            lsum += df * df;
        }
        float4 o4 = {ov[0], ov[1], ov[2], ov[3]};
        *(float4*)(ob + (size_t)d * T_ + q * 4) = o4;
    }

    red[tid] = lsum;
    __syncthreads();
    for (int s = 128; s > 0; s >>= 1) {
        if (tid < s) red[tid] += red[tid + s];
        __syncthreads();
    }
    if (tid == 0) atomicAdd(s_loss, red[0]);
}

// ---------------------------------------------------------------------------
// Inverted index construction: one atomic per ROW (65 K total, not 8.4 M)
// ---------------------------------------------------------------------------
__global__ void assign_kernel(const int* __restrict__ idx, int* __restrict__ cnt,
                              int* __restrict__ pos) {
    int n = blockIdx.x * 256 + threadIdx.x;
    pos[n] = atomicAdd(&cnt[idx[n]], 1);
}

// Exclusive prefix sum over 2048 counts, single block of 256 threads.
__global__ __launch_bounds__(256)
void scan_kernel(const int* __restrict__ cnt, int* __restrict__ offs) {
    __shared__ int part[256];
    const int tid = threadIdx.x;
    int loc[8];
    int s = 0;
#pragma unroll
    for (int j = 0; j < 8; j++) { loc[j] = s; s += cnt[tid * 8 + j]; }
    part[tid] = s;
    __syncthreads();
    for (int off = 1; off < 256; off <<= 1) {
        int v = (tid >= off) ? part[tid - off] : 0;
        __syncthreads();
        part[tid] += v;
        __syncthreads();
    }
    int pre = (tid == 0) ? 0 : part[tid - 1];
#pragma unroll
    for (int j = 0; j < 8; j++) offs[tid * 8 + j] = pre + loc[j];
    if (tid == 255) offs[2048] = pre + s;    // == N
}

__global__ void bucket_kernel(const int* __restrict__ idx, const int* __restrict__ pos,
                              const int* __restrict__ offs, int* __restrict__ row_list) {
    int n = blockIdx.x * 256 + threadIdx.x;
    row_list[offs[idx[n]] + pos[n]] = n;
}

// ---------------------------------------------------------------------------
// Per-code segment sum — zero atomics. Block per code, thread = d.
// z reads are 4B-strided but z is L2/L3 resident (32 MB, just read by argmin).
// ---------------------------------------------------------------------------
__global__ __launch_bounds__(128)
void sum_kernel(const float* __restrict__ z, const int* __restrict__ row_list,
                const int* __restrict__ offs, float* __restrict__ sum_new,
                float* __restrict__ elem_new) {
    const int k  = blockIdx.x;
    const int d  = threadIdx.x;          // 128
    const int lo = offs[k];
    const int hi = offs[k + 1];
    float acc = 0.0f;
    for (int i = lo; i < hi; i++) {
        int n = row_list[i];
        int b = n >> 11;                 // T = 2048
        int t = n & (T_ - 1);
        acc += z[(size_t)b * D_ * T_ + (size_t)d * T_ + t];
    }
    sum_new[k * D_ + d] = acc;
    if (d == 0) elem_new[k] = (float)(hi - lo);
}

// ---------------------------------------------------------------------------
// EMA update, emb_new select, dk / entropy partial sums
// ---------------------------------------------------------------------------
__global__ __launch_bounds__(256)
void update_kernel(const float* __restrict__ emb, const float* __restrict__ emb_sum,
                   const float* __restrict__ emb_elem, const float* __restrict__ emb_rand,
                   const float* __restrict__ sum_new, const float* __restrict__ elem_new,
                   float* __restrict__ out_emb_new, float* __restrict__ out_emb_sum_n,
                   float* __restrict__ out_emb_elem_n,
                   float* __restrict__ s_ent, float* __restrict__ s_dk) {
    const float MU  = 0.99f;
    const float OMM = (float)(1.0 - 0.99);   // match JAX's fp64 1.0-0.99 -> fp32
    int gid = blockIdx.x * 256 + threadIdx.x;   // < K_*D_ = 262144
    int k = gid >> 7;
    int d = gid & 127;

    float sn = sum_new[gid];
    float es = emb_sum[gid];
    float en = elem_new[k];
    float ee = emb_elem[k];
    float esn = MU * es + OMM * sn;
    float een = MU * ee + OMM * en;
    out_emb_sum_n[gid] = esn;
    float enew = (een >= 1.0f) ? (esn / een) : emb_rand[gid];
    out_emb_new[gid] = enew;

    float df = enew - emb[gid];
    float v  = df * df;
    __shared__ float red[256];
    red[threadIdx.x] = v;
    __syncthreads();
    for (int s = 128; s > 0; s >>= 1) {
        if (threadIdx.x < s) red[threadIdx.x] += red[threadIdx.x + s];
        __syncthreads();
    }
    if (threadIdx.x == 0) atomicAdd(s_dk, red[0]);

    if (d == 0) {
        out_emb_elem_n[k] = een;
        float p = en * (1.0f / 65536.0f);   // sum(elem_new) == N exactly in fp32
        atomicAdd(s_ent, p * logf(p + 1e-8f));
    }
}

// ---------------------------------------------------------------------------
// Scalar finalization
// ---------------------------------------------------------------------------
__global__ void final_kernel(const float* __restrict__ s_loss, const float* __restrict__ s_ent,
                             const float* __restrict__ s_dk,
                             float* __restrict__ out_loss, float* __restrict__ out_ent,
                             float* __restrict__ out_dk) {
    out_loss[0] = s_loss[0];
    out_ent[0]  = expf(-s_ent[0]);
    out_dk[0]   = sqrtf(s_dk[0]) * (1.0f / 512.0f);   // sqrt(K*D) = 512
}

// ---------------------------------------------------------------------------
extern "C" void kernel_launch(void* const* d_in, const int* in_sizes, int n_in,
                              void* d_out, int out_size, void* d_ws, size_t ws_size,
                              hipStream_t stream) {
    (void)in_sizes; (void)n_in; (void)out_size; (void)ws_size;

    const float* z        = (const float*)d_in[0];   // [32,128,2048]
    const float* emb      = (const float*)d_in[1];   // [2048,128]
    const float* emb_sum  = (const float*)d_in[2];   // [2048,128]
    const float* emb_elem = (const float*)d_in[3];   // [2048]
    const float* emb_rand = (const float*)d_in[4];   // [2048,128]

    float* out = (float*)d_out;
    float* out0            = out;                            // z_vq_out  8388608
    float* out_loss        = out + 8388608;                  // scalar
    float* out_emb_new     = out + 8388609;                  // 262144
    float* out_emb_sum_n   = out + 8388609 + 262144;         // 262144
    float* out_emb_elem_n  = out + 8388609 + 524288;         // 2048
    float* out_ent         = out + 8388609 + 524288 + 2048;  // scalar
    float* out_dk          = out_ent + 1;                    // scalar

    float* ws       = (float*)d_ws;
    int*   idx      = (int*)ws;              // 65536 ints
    float* hn       = ws + 65536;            // 2048
    float* sum_new  = ws + 67584;            // 262144
    float* elem_new = ws + 329728;           // 2048
    int*   cnt      = (int*)(ws + 331776);   // 2048 ints
    float* s_loss   = ws + 333824;
    float* s_ent    = ws + 333825;
    float* s_dk     = ws + 333826;
    int*   pos      = (int*)(ws + 333827);   // 65536 ints
    int*   offs     = (int*)(ws + 399363);   // 2049 ints
    int*   row_list = (int*)(ws + 401412);   // 65536 ints
                                             // total 466948 floats ~ 1.87 MB

    // zero cnt[2048] + 3 scalars (contiguous; 0.0f bit pattern == int 0)
    zero_kernel<<<(2051 + 255) / 256, 256, 0, stream>>>(ws + 331776, 2051);
    halfnorm_kernel<<<K_, 64, 0, stream>>>(emb, hn);
    argmin_kernel<<<N_ / 128, 256, 0, stream>>>(z, emb, hn, idx);
    assign_kernel<<<N_ / 256, 256, 0, stream>>>(idx, cnt, pos);
    scan_kernel<<<1, 256, 0, stream>>>(cnt, offs);
    bucket_kernel<<<N_ / 256, 256, 0, stream>>>(idx, pos, offs, row_list);
    ste_kernel<<<B_ * (T_ / 64), 256, 0, stream>>>(z, emb, idx, out0, s_loss);
    sum_kernel<<<K_, 128, 0, stream>>>(z, row_list, offs, sum_new, elem_new);
    update_kernel<<<(K_ * D_) / 256, 256, 0, stream>>>(emb, emb_sum, emb_elem, emb_rand,
                                                       sum_new, elem_new,
                                                       out_emb_new, out_emb_sum_n,
                                                       out_emb_elem_n, s_ent, s_dk);
    final_kernel<<<1, 1, 0, stream>>>(s_loss, s_ent, s_dk, out_loss, out_ent, out_dk);
}

// Round 3
// 754.672 us; speedup vs baseline: 2.5515x; 1.4840x over previous
//
#include <hip/hip_runtime.h>
#include <float.h>
#include <math.h>

// Problem constants (from reference setup_inputs)
#define B_   32
#define D_   128
#define T_   2048
#define K_   2048
#define N_   (B_ * T_)      // 65536

#define BD   16             // d-tile depth for argmin GEMM

// ---------------------------------------------------------------------------
// Zero scratch accumulators (harness re-poisons ws with 0xAA every launch)
// ---------------------------------------------------------------------------
__global__ void zero_kernel(float* __restrict__ p, int n) {
    int i = blockIdx.x * 256 + threadIdx.x;
    if (i < n) p[i] = 0.0f;
}

// ---------------------------------------------------------------------------
// halfnorm[k] = 0.5 * ||e_k||^2   (one wave per code)
// ---------------------------------------------------------------------------
__global__ void halfnorm_kernel(const float* __restrict__ emb, float* __restrict__ hn) {
    int k = blockIdx.x;
    int l = threadIdx.x;            // 64 threads = 1 wave
    float a = emb[(size_t)k * D_ + l];
    float b = emb[(size_t)k * D_ + 64 + l];
    float s = a * a + b * b;
#pragma unroll
    for (int off = 32; off > 0; off >>= 1) s += __shfl_down(s, off, 64);
    if (l == 0) hn[k] = 0.5f * s;
}

// ---------------------------------------------------------------------------
// Distance argmin: per row n, idx[n] = argmin_k (0.5*||e_k||^2 - z_n . e_k)
// Tiled fp32 "GEMM": block = 128 rows x 128 codes, 256 threads, 8x8 micro-tile.
// z is [B, D, T]; row n = b*T + t reads z[b*D*T + d*T + t] (coalesced over t).
// ---------------------------------------------------------------------------
__global__ __launch_bounds__(256)
void argmin_kernel(const float* __restrict__ z, const float* __restrict__ emb,
                   const float* __restrict__ hn, int* __restrict__ idx) {
    __shared__ float As[BD][128];       // z tile   (d-major)  8 KB
    __shared__ float Bs[BD][128];       // code tile (d-major) 8 KB
    __shared__ float redv[128][16];     // argmin reduce       8 KB
    __shared__ int   redi[128][16];     //                     8 KB

    const int tid = threadIdx.x;
    const int tx = tid & 15;            // code group
    const int ty = tid >> 4;            // row group
    const int n0 = blockIdx.x * 128;    // 512 blocks; 128 rows stay within one b
    const int b  = n0 >> 11;            // T = 2048
    const int t0 = n0 & (T_ - 1);
    const float* zb = z + (size_t)b * D_ * T_ + t0;

    float minv[8];
    int   mini[8];
#pragma unroll
    for (int i = 0; i < 8; i++) { minv[i] = FLT_MAX; mini[i] = 0; }

    const int a_di = tid >> 5;          // 0..7 (+8 on second pass)
    const int a_r  = (tid & 31) << 2;   // 0..124

    for (int k0 = 0; k0 < K_; k0 += 128) {
        float acc[8][8];
#pragma unroll
        for (int i = 0; i < 8; i++)
#pragma unroll
            for (int j = 0; j < 8; j++) acc[i][j] = 0.0f;

        for (int d0 = 0; d0 < D_; d0 += BD) {
            __syncthreads();
            // stage z tile: 128 rows x 16 d, float4 coalesced along t
#pragma unroll
            for (int p = 0; p < 2; p++) {
                int di = a_di + p * 8;
                float4 av = *(const float4*)(zb + (size_t)(d0 + di) * T_ + a_r);
                *(float4*)&As[di][a_r] = av;
            }
            // stage code tile: 128 codes x 16 d, float4 along d, transposed store
#pragma unroll
            for (int p = 0; p < 2; p++) {
                int c  = p * 256 + tid;
                int kk = c >> 2;
                int dq = c & 3;
                float4 bv = *(const float4*)(emb + (size_t)(k0 + kk) * D_ + d0 + dq * 4);
                Bs[dq * 4 + 0][kk] = bv.x;
                Bs[dq * 4 + 1][kk] = bv.y;
                Bs[dq * 4 + 2][kk] = bv.z;
                Bs[dq * 4 + 3][kk] = bv.w;
            }
            __syncthreads();
#pragma unroll
            for (int d = 0; d < BD; d++) {
                float4 a0 = *(const float4*)&As[d][ty * 4];
                float4 a1 = *(const float4*)&As[d][64 + ty * 4];
                float4 b0 = *(const float4*)&Bs[d][tx * 4];
                float4 b1 = *(const float4*)&Bs[d][64 + tx * 4];
                float a_[8] = {a0.x, a0.y, a0.z, a0.w, a1.x, a1.y, a1.z, a1.w};
                float b_[8] = {b0.x, b0.y, b0.z, b0.w, b1.x, b1.y, b1.z, b1.w};
#pragma unroll
                for (int i = 0; i < 8; i++)
#pragma unroll
                    for (int j = 0; j < 8; j++)
                        acc[i][j] += a_[i] * b_[j];
            }
        }
        // epilogue for this K-tile: score = halfnorm - dot; running argmin.
        // codes visited in ascending order within a thread -> strict < keeps first min.
#pragma unroll
        for (int j = 0; j < 8; j++) {
            int kidx = k0 + ((j < 4) ? (tx * 4 + j) : (64 + tx * 4 + (j - 4)));
            float h = hn[kidx];
#pragma unroll
            for (int i = 0; i < 8; i++) {
                float s = h - acc[i][j];
                if (s < minv[i]) { minv[i] = s; mini[i] = kidx; }
            }
        }
    }

    __syncthreads();
#pragma unroll
    for (int i = 0; i < 8; i++) {
        int r = (i < 4) ? (ty * 4 + i) : (64 + ty * 4 + (i - 4));
        redv[r][tx] = minv[i];
        redi[r][tx] = mini[i];
    }
    __syncthreads();
    if (tid < 128) {
        float bv = redv[tid][0];
        int   bi = redi[tid][0];
#pragma unroll
        for (int x = 1; x < 16; x++) {
            float v  = redv[tid][x];
            int   id = redi[tid][x];
            if (v < bv || (v == bv && id < bi)) { bv = v; bi = id; }
        }
        idx[n0 + tid] = bi;
    }
}

// ---------------------------------------------------------------------------
// STE output + loss + row-major transpose of z into zt[N][D].
// Block = 64 t x 128 d tile of one b. Coalesced float4 read of z, float4
// write of out0 (along t) and of zt (along d, via LDS transpose).
// LDS tile stride 129 (odd): store phase 2-way bank alias (free),
// read-out 4-way (1.58x) — ~1 us total, vs 490 us saved in sum_kernel.
// ---------------------------------------------------------------------------
__global__ __launch_bounds__(256)
void ste_kernel(const float* __restrict__ z, const float* __restrict__ emb,
                const int* __restrict__ idx, float* __restrict__ out0,
                float* __restrict__ zt, float* __restrict__ s_loss) {
    __shared__ int   scode[64];
    __shared__ float tile[64][129];          // [t_local][d], 32.25 KB
    __shared__ float red[256];
    const int tid = threadIdx.x;
    const int blk = blockIdx.x;              // 1024 blocks
    const int b   = blk >> 5;
    const int t0  = (blk & 31) * 64;
    const int n0  = b * T_ + t0;
    if (tid < 64) scode[tid] = idx[n0 + tid];
    __syncthreads();

    const float* zb = z    + (size_t)b * D_ * T_ + t0;
    float*       ob = out0 + (size_t)b * D_ * T_ + t0;
    float lsum = 0.0f;
#pragma unroll
    for (int it = 0; it < 8; it++) {
        int flat = it * 256 + tid;           // 0..2047 covers 128 d x 16 q
        int d = flat >> 4;
        int q = flat & 15;
        float4 zv = *(const float4*)(zb + (size_t)d * T_ + q * 4);
        float zi[4] = {zv.x, zv.y, zv.z, zv.w};
        float ov[4];
#pragma unroll
        for (int j = 0; j < 4; j++) {
            tile[q * 4 + j][d] = zi[j];      // transpose stage
            int code = scode[q * 4 + j];
            float e  = emb[(size_t)code * D_ + d];
            float df = e - zi[j];            // z_vq - zf (one rounding)
            ov[j] = zi[j] + df;              // zf + (z_vq - zf), matches reference STE
            lsum += df * df;
        }
        float4 o4 = {ov[0], ov[1], ov[2], ov[3]};
        *(float4*)(ob + (size_t)d * T_ + q * 4) = o4;
    }
    __syncthreads();
    // write zt rows: 64 rows x 128 d, float4 along d; 8 rows per iteration
#pragma unroll
    for (int it = 0; it < 8; it++) {
        int r  = it * 8 + (tid >> 5);
        int dq = (tid & 31) * 4;
        float4 v = {tile[r][dq], tile[r][dq + 1], tile[r][dq + 2], tile[r][dq + 3]};
        *(float4*)(zt + (size_t)(n0 + r) * D_ + dq) = v;
    }

    red[tid] = lsum;
    __syncthreads();
    for (int s = 128; s > 0; s >>= 1) {
        if (tid < s) red[tid] += red[tid + s];
        __syncthreads();
    }
    if (tid == 0) atomicAdd(s_loss, red[0]);
}

// ---------------------------------------------------------------------------
// Inverted index construction: one atomic per ROW (65 K total, not 8.4 M)
// ---------------------------------------------------------------------------
__global__ void assign_kernel(const int* __restrict__ idx, int* __restrict__ cnt,
                              int* __restrict__ pos) {
    int n = blockIdx.x * 256 + threadIdx.x;
    pos[n] = atomicAdd(&cnt[idx[n]], 1);
}

// Exclusive prefix sum over 2048 counts, single block of 256 threads.
__global__ __launch_bounds__(256)
void scan_kernel(const int* __restrict__ cnt, int* __restrict__ offs) {
    __shared__ int part[256];
    const int tid = threadIdx.x;
    int loc[8];
    int s = 0;
#pragma unroll
    for (int j = 0; j < 8; j++) { loc[j] = s; s += cnt[tid * 8 + j]; }
    part[tid] = s;
    __syncthreads();
    for (int off = 1; off < 256; off <<= 1) {
        int v = (tid >= off) ? part[tid - off] : 0;
        __syncthreads();
        part[tid] += v;
        __syncthreads();
    }
    int pre = (tid == 0) ? 0 : part[tid - 1];
#pragma unroll
    for (int j = 0; j < 8; j++) offs[tid * 8 + j] = pre + loc[j];
    if (tid == 255) offs[2048] = pre + s;    // == N
}

__global__ void bucket_kernel(const int* __restrict__ idx, const int* __restrict__ pos,
                              const int* __restrict__ offs, int* __restrict__ row_list) {
    int n = blockIdx.x * 256 + threadIdx.x;
    row_list[offs[idx[n]] + pos[n]] = n;
}

// ---------------------------------------------------------------------------
// Per-code segment sum from row-major zt — zero atomics, coalesced 512 B rows.
// Block per code, 128 threads = 4 groups of 32 lanes; lane reads float4 of d.
// ---------------------------------------------------------------------------
__global__ __launch_bounds__(128)
void sum_kernel(const float* __restrict__ zt, const int* __restrict__ row_list,
                const int* __restrict__ offs, float* __restrict__ sum_new,
                float* __restrict__ elem_new) {
    __shared__ float part[4][132];
    const int k  = blockIdx.x;
    const int g  = threadIdx.x >> 5;     // row group 0..3
    const int l  = threadIdx.x & 31;     // lane -> d quad
    const int lo = offs[k];
    const int hi = offs[k + 1];
    float4 acc = {0.0f, 0.0f, 0.0f, 0.0f};
    for (int i = lo + g; i < hi; i += 4) {
        int n = row_list[i];
        float4 v = *(const float4*)(zt + (size_t)n * D_ + l * 4);
        acc.x += v.x; acc.y += v.y; acc.z += v.z; acc.w += v.w;
    }
    part[g][l * 4 + 0] = acc.x;
    part[g][l * 4 + 1] = acc.y;
    part[g][l * 4 + 2] = acc.z;
    part[g][l * 4 + 3] = acc.w;
    __syncthreads();
    int d = threadIdx.x;                 // 0..127
    sum_new[k * D_ + d] = part[0][d] + part[1][d] + part[2][d] + part[3][d];
    if (d == 0) elem_new[k] = (float)(hi - lo);
}

// ---------------------------------------------------------------------------
// EMA update, emb_new select, dk / entropy partial sums
// ---------------------------------------------------------------------------
__global__ __launch_bounds__(256)
void update_kernel(const float* __restrict__ emb, const float* __restrict__ emb_sum,
                   const float* __restrict__ emb_elem, const float* __restrict__ emb_rand,
                   const float* __restrict__ sum_new, const float* __restrict__ elem_new,
                   float* __restrict__ out_emb_new, float* __restrict__ out_emb_sum_n,
                   float* __restrict__ out_emb_elem_n,
                   float* __restrict__ s_ent, float* __restrict__ s_dk) {
    const float MU  = 0.99f;
    const float OMM = (float)(1.0 - 0.99);   // match JAX's fp64 1.0-0.99 -> fp32
    int gid = blockIdx.x * 256 + threadIdx.x;   // < K_*D_ = 262144
    int k = gid >> 7;
    int d = gid & 127;

    float sn = sum_new[gid];
    float es = emb_sum[gid];
    float en = elem_new[k];
    float ee = emb_elem[k];
    float esn = MU * es + OMM * sn;
    float een = MU * ee + OMM * en;
    out_emb_sum_n[gid] = esn;
    float enew = (een >= 1.0f) ? (esn / een) : emb_rand[gid];
    out_emb_new[gid] = enew;

    float df = enew - emb[gid];
    float v  = df * df;
    __shared__ float red[256];
    red[threadIdx.x] = v;
    __syncthreads();
    for (int s = 128; s > 0; s >>= 1) {
        if (threadIdx.x < s) red[threadIdx.x] += red[threadIdx.x + s];
        __syncthreads();
    }
    if (threadIdx.x == 0) atomicAdd(s_dk, red[0]);

    if (d == 0) {
        out_emb_elem_n[k] = een;
        float p = en * (1.0f / 65536.0f);   // sum(elem_new) == N exactly in fp32
        atomicAdd(s_ent, p * logf(p + 1e-8f));
    }
}

// ---------------------------------------------------------------------------
// Scalar finalization
// ---------------------------------------------------------------------------
__global__ void final_kernel(const float* __restrict__ s_loss, const float* __restrict__ s_ent,
                             const float* __restrict__ s_dk,
                             float* __restrict__ out_loss, float* __restrict__ out_ent,
                             float* __restrict__ out_dk) {
    out_loss[0] = s_loss[0];
    out_ent[0]  = expf(-s_ent[0]);
    out_dk[0]   = sqrtf(s_dk[0]) * (1.0f / 512.0f);   // sqrt(K*D) = 512
}

// ---------------------------------------------------------------------------
extern "C" void kernel_launch(void* const* d_in, const int* in_sizes, int n_in,
                              void* d_out, int out_size, void* d_ws, size_t ws_size,
                              hipStream_t stream) {
    (void)in_sizes; (void)n_in; (void)out_size; (void)ws_size;

    const float* z        = (const float*)d_in[0];   // [32,128,2048]
    const float* emb      = (const float*)d_in[1];   // [2048,128]
    const float* emb_sum  = (const float*)d_in[2];   // [2048,128]
    const float* emb_elem = (const float*)d_in[3];   // [2048]
    const float* emb_rand = (const float*)d_in[4];   // [2048,128]

    float* out = (float*)d_out;
    float* out0            = out;                            // z_vq_out  8388608
    float* out_loss        = out + 8388608;                  // scalar
    float* out_emb_new     = out + 8388609;                  // 262144
    float* out_emb_sum_n   = out + 8388609 + 262144;         // 262144
    float* out_emb_elem_n  = out + 8388609 + 524288;         // 2048
    float* out_ent         = out + 8388609 + 524288 + 2048;  // scalar
    float* out_dk          = out_ent + 1;                    // scalar

    float* ws       = (float*)d_ws;
    float* zt       = ws;                        // 8388608 (32 MB, row-major z)
    int*   idx      = (int*)(ws + 8388608);      // 65536 ints
    float* hn       = ws + 8454144;              // 2048
    float* sum_new  = ws + 8456192;              // 262144
    float* elem_new = ws + 8718336;              // 2048
    int*   cnt      = (int*)(ws + 8720384);      // 2048 ints
    float* s_loss   = ws + 8722432;
    float* s_ent    = ws + 8722433;
    float* s_dk     = ws + 8722434;
    int*   pos      = (int*)(ws + 8722435);      // 65536 ints
    int*   offs     = (int*)(ws + 8787971);      // 2049 ints
    int*   row_list = (int*)(ws + 8790020);      // 65536 ints
                                                 // end: 8855556 floats ~ 35.4 MB

    // zero cnt[2048] + 3 scalars (contiguous; 0.0f bit pattern == int 0)
    zero_kernel<<<(2051 + 255) / 256, 256, 0, stream>>>(ws + 8720384, 2051);
    halfnorm_kernel<<<K_, 64, 0, stream>>>(emb, hn);
    argmin_kernel<<<N_ / 128, 256, 0, stream>>>(z, emb, hn, idx);
    assign_kernel<<<N_ / 256, 256, 0, stream>>>(idx, cnt, pos);
    scan_kernel<<<1, 256, 0, stream>>>(cnt, offs);
    bucket_kernel<<<N_ / 256, 256, 0, stream>>>(idx, pos, offs, row_list);
    ste_kernel<<<B_ * (T_ / 64), 256, 0, stream>>>(z, emb, idx, out0, zt, s_loss);
    sum_kernel<<<K_, 128, 0, stream>>>(zt, row_list, offs, sum_new, elem_new);
    update_kernel<<<(K_ * D_) / 256, 256, 0, stream>>>(emb, emb_sum, emb_elem, emb_rand,
                                                       sum_new, elem_new,
                                                       out_emb_new, out_emb_sum_n,
                                                       out_emb_elem_n, s_ent, s_dk);
    final_kernel<<<1, 1, 0, stream>>>(s_loss, s_ent, s_dk, out_loss, out_ent, out_dk);
}

// Round 4
// 647.518 us; speedup vs baseline: 2.9737x; 1.1655x over previous
//
#include <hip/hip_runtime.h>
#include <float.h>
#include <math.h>

// Problem constants (from reference setup_inputs)
#define B_   32
#define D_   128
#define T_   2048
#define K_   2048
#define N_   (B_ * T_)      // 65536

typedef _Float16 f16;
typedef f16   f16x8 __attribute__((ext_vector_type(8)));
typedef f16   f16x4 __attribute__((ext_vector_type(4)));
typedef float f32x4 __attribute__((ext_vector_type(4)));

// async global->LDS, 16 B per lane, LDS dst = wave-uniform base + lane*16
__device__ __forceinline__ void load_lds16(const void* g, void* l) {
    __builtin_amdgcn_global_load_lds(
        (const __attribute__((address_space(1))) unsigned int*)g,
        (__attribute__((address_space(3))) unsigned int*)l, 16, 0, 0);
}

// ---------------------------------------------------------------------------
// Zero scratch accumulators (harness re-poisons ws with 0xAA every launch)
// ---------------------------------------------------------------------------
__global__ void zero_kernel(float* __restrict__ p, int n) {
    int i = blockIdx.x * 256 + threadIdx.x;
    if (i < n) p[i] = 0.0f;
}

// ---------------------------------------------------------------------------
// emb -> (eh, el) fp16 split + halfnorm. One wave per code.
// ---------------------------------------------------------------------------
__global__ void eprep_kernel(const float* __restrict__ emb, f16* __restrict__ eh,
                             f16* __restrict__ el, float* __restrict__ hn) {
    int k = blockIdx.x;
    int l = threadIdx.x;            // 64
    float a = emb[(size_t)k * D_ + l];
    float b = emb[(size_t)k * D_ + 64 + l];
    f16 ah = (f16)a; f16 al = (f16)(a - (float)ah);
    f16 bh = (f16)b; f16 bl = (f16)(b - (float)bh);
    eh[(size_t)k * D_ + l]      = ah;
    eh[(size_t)k * D_ + 64 + l] = bh;
    el[(size_t)k * D_ + l]      = al;
    el[(size_t)k * D_ + 64 + l] = bl;
    float s = a * a + b * b;
#pragma unroll
    for (int off = 32; off > 0; off >>= 1) s += __shfl_down(s, off, 64);
    if (l == 0) hn[k] = 0.5f * s;
}

// ---------------------------------------------------------------------------
// z [B,D,T] -> row-major fp16 split zh[N][D], zl[N][D] (transpose via LDS)
// ---------------------------------------------------------------------------
__global__ __launch_bounds__(256)
void prep_kernel(const float* __restrict__ z, f16* __restrict__ zh, f16* __restrict__ zl) {
    __shared__ float tile[64][129];
    const int tid = threadIdx.x;
    const int blk = blockIdx.x;              // 1024
    const int b   = blk >> 5;
    const int t0  = (blk & 31) * 64;
    const int n0  = b * T_ + t0;
    const float* zb = z + (size_t)b * D_ * T_ + t0;
#pragma unroll
    for (int it = 0; it < 8; it++) {
        int flat = it * 256 + tid;           // 128 d x 16 q
        int d = flat >> 4;
        int q = flat & 15;
        float4 zv = *(const float4*)(zb + (size_t)d * T_ + q * 4);
        tile[q * 4 + 0][d] = zv.x;
        tile[q * 4 + 1][d] = zv.y;
        tile[q * 4 + 2][d] = zv.z;
        tile[q * 4 + 3][d] = zv.w;
    }
    __syncthreads();
#pragma unroll
    for (int it = 0; it < 8; it++) {
        int r  = it * 8 + (tid >> 5);
        int d0 = (tid & 31) * 4;
        f16x4 hv, lv;
#pragma unroll
        for (int j = 0; j < 4; j++) {
            float v = tile[r][d0 + j];
            f16 hh = (f16)v;
            f16 ll = (f16)(v - (float)hh);
            if (j == 0) { hv.x = hh; lv.x = ll; }
            if (j == 1) { hv.y = hh; lv.y = ll; }
            if (j == 2) { hv.z = hh; lv.z = ll; }
            if (j == 3) { hv.w = hh; lv.w = ll; }
        }
        *(f16x4*)&zh[(size_t)(n0 + r) * D_ + d0] = hv;
        *(f16x4*)&zl[(size_t)(n0 + r) * D_ + d0] = lv;
    }
}

// ---------------------------------------------------------------------------
// MFMA distance-argmin partials. dot(z,e) via split-fp16, K_eff = 384:
//   A_eff = [zh | zh | zl], B_eff = [eh | el | eh]   (error ~2^-22 |z.e|)
// m97 structure: 128 rows x 128 codes per block, 4 waves (2x2 of 64x64),
// BK=64, global_load_lds width 16, XOR seg-swizzled LDS, ds_read_b128 frags,
// mfma_f32_16x16x32_f16. Epilogue: per-row argmin over the 128 codes ->
// partial (minv, mini) written to Pv/Pi[n][kb].
// ---------------------------------------------------------------------------
__global__ __launch_bounds__(256)
void argmin_mfma(const f16* __restrict__ zh, const f16* __restrict__ zl,
                 const f16* __restrict__ eh, const f16* __restrict__ el,
                 const float* __restrict__ hn,
                 float* __restrict__ Pv, int* __restrict__ Pi) {
    __shared__ f16 As[128 * 64];         // 16 KB  [row][64h], seg-swizzled
    __shared__ f16 Bs[128 * 64];         // 16 KB
    __shared__ float redv2[128][2];
    __shared__ int   redi2[128][2];

    const int tid = threadIdx.x;
    const int w   = tid >> 6;            // wave 0..3
    const int l   = tid & 63;
    const int wm  = w >> 1;              // row-half of tile
    const int wn  = w & 1;               // col-half of tile
    const int mb  = blockIdx.x >> 4;     // 0..511
    const int kb  = blockIdx.x & 15;     // 0..15 (consecutive blocks share A rows)
    const int n0  = mb * 128;
    const int k0  = kb * 128;

    // K_eff chunk source tables (64 halves per chunk)
    const f16* Asrc[6] = {zh, zh, zh, zh, zl, zl};
    const f16* Bsrc[6] = {eh, eh, el, el, eh, eh};
    const int  Coff[6] = {0, 64, 0, 64, 0, 64};

    f32x4 acc[4][4];
#pragma unroll
    for (int mi = 0; mi < 4; mi++)
#pragma unroll
        for (int ni = 0; ni < 4; ni++) acc[mi][ni] = (f32x4){0.f, 0.f, 0.f, 0.f};

    const int rl = l >> 3;               // staging row-within-8
    const int sg = (l & 7) ^ (rl & 7);   // XOR seg swizzle (matches readers)

    for (int c = 0; c < 6; c++) {
        __syncthreads();
        const f16* ap = Asrc[c];
        const f16* bp = Bsrc[c];
        const int  co = Coff[c];
#pragma unroll
        for (int i = 0; i < 4; i++) {
            int row = w * 32 + i * 8 + rl;       // LDS row == tile row
            load_lds16(ap + (size_t)(n0 + row) * D_ + co + sg * 8,
                       &As[(w * 32 + i * 8) * 64]);
            load_lds16(bp + (size_t)(k0 + row) * D_ + co + sg * 8,
                       &Bs[(w * 32 + i * 8) * 64]);
        }
        __syncthreads();
#pragma unroll
        for (int s = 0; s < 2; s++) {
            f16x8 af[4], bf[4];
#pragma unroll
            for (int mi = 0; mi < 4; mi++) {
                int m  = wm * 64 + mi * 16 + (l & 15);
                int sl = (s * 4 + (l >> 4)) ^ (m & 7);
                af[mi] = *(const f16x8*)&As[m * 64 + sl * 8];
            }
#pragma unroll
            for (int ni = 0; ni < 4; ni++) {
                int n  = wn * 64 + ni * 16 + (l & 15);
                int sl = (s * 4 + (l >> 4)) ^ (n & 7);
                bf[ni] = *(const f16x8*)&Bs[n * 64 + sl * 8];
            }
#pragma unroll
            for (int mi = 0; mi < 4; mi++)
#pragma unroll
                for (int ni = 0; ni < 4; ni++)
                    acc[mi][ni] = __builtin_amdgcn_mfma_f32_16x16x32_f16(
                        af[mi], bf[ni], acc[mi][ni], 0, 0, 0);
        }
    }

    // epilogue: score = hn[k] - dot; per-row argmin (first-min tie-break)
    float hnv[4];
    int   cidx[4];
#pragma unroll
    for (int ni = 0; ni < 4; ni++) {
        cidx[ni] = k0 + wn * 64 + ni * 16 + (l & 15);
        hnv[ni]  = hn[cidx[ni]];
    }
    const int q = l >> 4;
#pragma unroll
    for (int mi = 0; mi < 4; mi++) {
#pragma unroll
        for (int r = 0; r < 4; r++) {
            float bv = FLT_MAX;
            int   bi = 0x7fffffff;
#pragma unroll
            for (int ni = 0; ni < 4; ni++) {
                float sc = hnv[ni] - acc[mi][ni][r];
                if (sc < bv || (sc == bv && cidx[ni] < bi)) { bv = sc; bi = cidx[ni]; }
            }
            // reduce across the 16 lanes holding this row
#pragma unroll
            for (int msk = 1; msk < 16; msk <<= 1) {
                float ov = __shfl_xor(bv, msk, 64);
                int   oi = __shfl_xor(bi, msk, 64);
                if (ov < bv || (ov == bv && oi < bi)) { bv = ov; bi = oi; }
            }
            if ((l & 15) == 0) {
                int row = wm * 64 + mi * 16 + q * 4 + r;
                redv2[row][wn] = bv;
                redi2[row][wn] = bi;
            }
        }
    }
    __syncthreads();
    if (tid < 128) {
        float v0 = redv2[tid][0]; int i0 = redi2[tid][0];
        float v1 = redv2[tid][1]; int i1 = redi2[tid][1];
        if (v1 < v0 || (v1 == v0 && i1 < i0)) { v0 = v1; i0 = i1; }
        Pv[(size_t)(n0 + tid) * 16 + kb] = v0;
        Pi[(size_t)(n0 + tid) * 16 + kb] = i0;
    }
}

// Reduce 16 per-row partials -> idx[n]
__global__ void argmin_reduce(const float* __restrict__ Pv, const int* __restrict__ Pi,
                              int* __restrict__ idx) {
    int n = blockIdx.x * 256 + threadIdx.x;
    float bv = Pv[(size_t)n * 16];
    int   bi = Pi[(size_t)n * 16];
#pragma unroll
    for (int j = 1; j < 16; j++) {
        float v = Pv[(size_t)n * 16 + j];
        int   i = Pi[(size_t)n * 16 + j];
        if (v < bv || (v == bv && i < bi)) { bv = v; bi = i; }
    }
    idx[n] = bi;
}

// ---------------------------------------------------------------------------
// STE output + loss: block = 64 t x 128 d tile of one b. Coalesced float4
// read/write of z/out0; codebook gather is L2-resident (emb = 1 MB).
// ---------------------------------------------------------------------------
__global__ __launch_bounds__(256)
void ste_kernel(const float* __restrict__ z, const float* __restrict__ emb,
                const int* __restrict__ idx, float* __restrict__ out0,
                float* __restrict__ s_loss) {
    __shared__ int   scode[64];
    __shared__ float red[256];
    const int tid = threadIdx.x;
    const int blk = blockIdx.x;              // 1024
    const int b   = blk >> 5;
    const int t0  = (blk & 31) * 64;
    const int n0  = b * T_ + t0;
    if (tid < 64) scode[tid] = idx[n0 + tid];
    __syncthreads();

    const float* zb = z    + (size_t)b * D_ * T_ + t0;
    float*       ob = out0 + (size_t)b * D_ * T_ + t0;
    float lsum = 0.0f;
#pragma unroll
    for (int it = 0; it < 8; it++) {
        int flat = it * 256 + tid;
        int d = flat >> 4;
        int q = flat & 15;
        float4 zv = *(const float4*)(zb + (size_t)d * T_ + q * 4);
        float zi[4] = {zv.x, zv.y, zv.z, zv.w};
        float ov[4];
#pragma unroll
        for (int j = 0; j < 4; j++) {
            int code = scode[q * 4 + j];
            float e  = emb[(size_t)code * D_ + d];
            float df = e - zi[j];            // z_vq - zf (one rounding)
            ov[j] = zi[j] + df;              // zf + (z_vq - zf), matches reference STE
            lsum += df * df;
        }
        float4 o4 = {ov[0], ov[1], ov[2], ov[3]};
        *(float4*)(ob + (size_t)d * T_ + q * 4) = o4;
    }

    red[tid] = lsum;
    __syncthreads();
    for (int s = 128; s > 0; s >>= 1) {
        if (tid < s) red[tid] += red[tid + s];
        __syncthreads();
    }
    if (tid == 0) atomicAdd(s_loss, red[0]);
}

// ---------------------------------------------------------------------------
// Inverted index construction: one atomic per ROW (65 K total, not 8.4 M)
// ---------------------------------------------------------------------------
__global__ void assign_kernel(const int* __restrict__ idx, int* __restrict__ cnt,
                              int* __restrict__ pos) {
    int n = blockIdx.x * 256 + threadIdx.x;
    pos[n] = atomicAdd(&cnt[idx[n]], 1);
}

// Exclusive prefix sum over 2048 counts, single block of 256 threads.
__global__ __launch_bounds__(256)
void scan_kernel(const int* __restrict__ cnt, int* __restrict__ offs) {
    __shared__ int part[256];
    const int tid = threadIdx.x;
    int loc[8];
    int s = 0;
#pragma unroll
    for (int j = 0; j < 8; j++) { loc[j] = s; s += cnt[tid * 8 + j]; }
    part[tid] = s;
    __syncthreads();
    for (int off = 1; off < 256; off <<= 1) {
        int v = (tid >= off) ? part[tid - off] : 0;
        __syncthreads();
        part[tid] += v;
        __syncthreads();
    }
    int pre = (tid == 0) ? 0 : part[tid - 1];
#pragma unroll
    for (int j = 0; j < 8; j++) offs[tid * 8 + j] = pre + loc[j];
    if (tid == 255) offs[2048] = pre + s;    // == N
}

__global__ void bucket_kernel(const int* __restrict__ idx, const int* __restrict__ pos,
                              const int* __restrict__ offs, int* __restrict__ row_list) {
    int n = blockIdx.x * 256 + threadIdx.x;
    row_list[offs[idx[n]] + pos[n]] = n;
}

// ---------------------------------------------------------------------------
// Per-code segment sum from zh+zl (hi+lo sum is exact fp32) — zero atomics,
// coalesced 256 B rows. Block per code, 4 row-groups x 32 lanes (d quads).
// ---------------------------------------------------------------------------
__global__ __launch_bounds__(128)
void sum_kernel(const f16* __restrict__ zh, const f16* __restrict__ zl,
                const int* __restrict__ row_list, const int* __restrict__ offs,
                float* __restrict__ sum_new, float* __restrict__ elem_new) {
    __shared__ float part[4][132];
    const int k  = blockIdx.x;
    const int g  = threadIdx.x >> 5;     // row group 0..3
    const int l  = threadIdx.x & 31;     // lane -> d quad
    const int lo = offs[k];
    const int hi = offs[k + 1];
    float4 acc = {0.0f, 0.0f, 0.0f, 0.0f};
    for (int i = lo + g; i < hi; i += 4) {
        int n = row_list[i];
        f16x4 hv = *(const f16x4*)&zh[(size_t)n * D_ + l * 4];
        f16x4 lv = *(const f16x4*)&zl[(size_t)n * D_ + l * 4];
        acc.x += (float)hv.x + (float)lv.x;
        acc.y += (float)hv.y + (float)lv.y;
        acc.z += (float)hv.z + (float)lv.z;
        acc.w += (float)hv.w + (float)lv.w;
    }
    part[g][l * 4 + 0] = acc.x;
    part[g][l * 4 + 1] = acc.y;
    part[g][l * 4 + 2] = acc.z;
    part[g][l * 4 + 3] = acc.w;
    __syncthreads();
    int d = threadIdx.x;
    sum_new[k * D_ + d] = part[0][d] + part[1][d] + part[2][d] + part[3][d];
    if (d == 0) elem_new[k] = (float)(hi - lo);
}

// ---------------------------------------------------------------------------
// EMA update, emb_new select, dk / entropy partial sums
// ---------------------------------------------------------------------------
__global__ __launch_bounds__(256)
void update_kernel(const float* __restrict__ emb, const float* __restrict__ emb_sum,
                   const float* __restrict__ emb_elem, const float* __restrict__ emb_rand,
                   const float* __restrict__ sum_new, const float* __restrict__ elem_new,
                   float* __restrict__ out_emb_new, float* __restrict__ out_emb_sum_n,
                   float* __restrict__ out_emb_elem_n,
                   float* __restrict__ s_ent, float* __restrict__ s_dk) {
    const float MU  = 0.99f;
    const float OMM = (float)(1.0 - 0.99);   // match JAX's fp64 1.0-0.99 -> fp32
    int gid = blockIdx.x * 256 + threadIdx.x;   // < K_*D_ = 262144
    int k = gid >> 7;
    int d = gid & 127;

    float sn = sum_new[gid];
    float es = emb_sum[gid];
    float en = elem_new[k];
    float ee = emb_elem[k];
    float esn = MU * es + OMM * sn;
    float een = MU * ee + OMM * en;
    out_emb_sum_n[gid] = esn;
    float enew = (een >= 1.0f) ? (esn / een) : emb_rand[gid];
    out_emb_new[gid] = enew;

    float df = enew - emb[gid];
    float v  = df * df;
    __shared__ float red[256];
    red[threadIdx.x] = v;
    __syncthreads();
    for (int s = 128; s > 0; s >>= 1) {
        if (threadIdx.x < s) red[threadIdx.x] += red[threadIdx.x + s];
        __syncthreads();
    }
    if (threadIdx.x == 0) atomicAdd(s_dk, red[0]);

    if (d == 0) {
        out_emb_elem_n[k] = een;
        float p = en * (1.0f / 65536.0f);   // sum(elem_new) == N exactly in fp32
        atomicAdd(s_ent, p * logf(p + 1e-8f));
    }
}

// ---------------------------------------------------------------------------
// Scalar finalization
// ---------------------------------------------------------------------------
__global__ void final_kernel(const float* __restrict__ s_loss, const float* __restrict__ s_ent,
                             const float* __restrict__ s_dk,
                             float* __restrict__ out_loss, float* __restrict__ out_ent,
                             float* __restrict__ out_dk) {
    out_loss[0] = s_loss[0];
    out_ent[0]  = expf(-s_ent[0]);
    out_dk[0]   = sqrtf(s_dk[0]) * (1.0f / 512.0f);   // sqrt(K*D) = 512
}

// ---------------------------------------------------------------------------
extern "C" void kernel_launch(void* const* d_in, const int* in_sizes, int n_in,
                              void* d_out, int out_size, void* d_ws, size_t ws_size,
                              hipStream_t stream) {
    (void)in_sizes; (void)n_in; (void)out_size; (void)ws_size;

    const float* z        = (const float*)d_in[0];   // [32,128,2048]
    const float* emb      = (const float*)d_in[1];   // [2048,128]
    const float* emb_sum  = (const float*)d_in[2];   // [2048,128]
    const float* emb_elem = (const float*)d_in[3];   // [2048]
    const float* emb_rand = (const float*)d_in[4];   // [2048,128]

    float* out = (float*)d_out;
    float* out0            = out;                            // z_vq_out  8388608
    float* out_loss        = out + 8388608;                  // scalar
    float* out_emb_new     = out + 8388609;                  // 262144
    float* out_emb_sum_n   = out + 8388609 + 262144;         // 262144
    float* out_emb_elem_n  = out + 8388609 + 524288;         // 2048
    float* out_ent         = out + 8388609 + 524288 + 2048;  // scalar
    float* out_dk          = out_ent + 1;                    // scalar

    float* ws = (float*)d_ws;                     // offsets in floats
    f16*   zh       = (f16*)(ws);                 // 8388608 halves (4194304 f)
    f16*   zl       = (f16*)(ws + 4194304);       // 8388608 halves
    float* Pv       = ws + 8388608;               // 1048576
    int*   Pi       = (int*)(ws + 9437184);       // 1048576
    int*   idx      = (int*)(ws + 10485760);      // 65536
    float* hn       = ws + 10551296;              // 2048
    f16*   eh       = (f16*)(ws + 10553344);      // 262144 halves (131072 f)
    f16*   el       = (f16*)(ws + 10684416);      // 262144 halves
    float* sum_new  = ws + 10815488;              // 262144
    float* elem_new = ws + 11077632;              // 2048
    int*   cnt      = (int*)(ws + 11079680);      // 2048
    float* s_loss   = ws + 11081728;
    float* s_ent    = ws + 11081729;
    float* s_dk     = ws + 11081730;
    int*   pos      = (int*)(ws + 11081731);      // 65536
    int*   offs     = (int*)(ws + 11147267);      // 2049
    int*   row_list = (int*)(ws + 11149316);      // 65536
                                                  // end 11214852 f ~ 44.9 MB

    // zero cnt[2048] + 3 scalars (contiguous)
    zero_kernel<<<(2051 + 255) / 256, 256, 0, stream>>>(ws + 11079680, 2051);
    eprep_kernel<<<K_, 64, 0, stream>>>(emb, eh, el, hn);
    prep_kernel<<<B_ * (T_ / 64), 256, 0, stream>>>(z, zh, zl);
    argmin_mfma<<<(N_ / 128) * 16, 256, 0, stream>>>(zh, zl, eh, el, hn, Pv, Pi);
    argmin_reduce<<<N_ / 256, 256, 0, stream>>>(Pv, Pi, idx);
    assign_kernel<<<N_ / 256, 256, 0, stream>>>(idx, cnt, pos);
    scan_kernel<<<1, 256, 0, stream>>>(cnt, offs);
    bucket_kernel<<<N_ / 256, 256, 0, stream>>>(idx, pos, offs, row_list);
    ste_kernel<<<B_ * (T_ / 64), 256, 0, stream>>>(z, emb, idx, out0, s_loss);
    sum_kernel<<<K_, 128, 0, stream>>>(zh, zl, row_list, offs, sum_new, elem_new);
    update_kernel<<<(K_ * D_) / 256, 256, 0, stream>>>(emb, emb_sum, emb_elem, emb_rand,
                                                       sum_new, elem_new,
                                                       out_emb_new, out_emb_sum_n,
                                                       out_emb_elem_n, s_ent, s_dk);
    final_kernel<<<1, 1, 0, stream>>>(s_loss, s_ent, s_dk, out_loss, out_ent, out_dk);
}

// Round 5
// 470.349 us; speedup vs baseline: 4.0939x; 1.3767x over previous
//
#include <hip/hip_runtime.h>
#include <float.h>
#include <math.h>

// Problem constants (from reference setup_inputs)
#define B_   32
#define D_   128
#define T_   2048
#define K_   2048
#define N_   (B_ * T_)      // 65536

typedef _Float16 f16;
typedef f16   f16x8 __attribute__((ext_vector_type(8)));
typedef f16   f16x4 __attribute__((ext_vector_type(4)));
typedef float f32x4 __attribute__((ext_vector_type(4)));

// async global->LDS, 16 B per lane, LDS dst = wave-uniform base + lane*16
__device__ __forceinline__ void load_lds16(const void* g, void* l) {
    __builtin_amdgcn_global_load_lds(
        (const __attribute__((address_space(1))) unsigned int*)g,
        (__attribute__((address_space(3))) unsigned int*)l, 16, 0, 0);
}

// ---------------------------------------------------------------------------
// emb -> (eh, el) fp16 split + halfnorm. One wave per code.
// Also zeroes cnt[k] and the 3 scalar accumulators (fused old zero_kernel).
// ---------------------------------------------------------------------------
__global__ void eprep_kernel(const float* __restrict__ emb, f16* __restrict__ eh,
                             f16* __restrict__ el, float* __restrict__ hn,
                             int* __restrict__ cnt, float* __restrict__ scalars) {
    int k = blockIdx.x;
    int l = threadIdx.x;            // 64
    if (l == 0) cnt[k] = 0;
    if (k == 0 && l < 3) scalars[l] = 0.0f;
    float a = emb[(size_t)k * D_ + l];
    float b = emb[(size_t)k * D_ + 64 + l];
    f16 ah = (f16)a; f16 al = (f16)(a - (float)ah);
    f16 bh = (f16)b; f16 bl = (f16)(b - (float)bh);
    eh[(size_t)k * D_ + l]      = ah;
    eh[(size_t)k * D_ + 64 + l] = bh;
    el[(size_t)k * D_ + l]      = al;
    el[(size_t)k * D_ + 64 + l] = bl;
    float s = a * a + b * b;
#pragma unroll
    for (int off = 32; off > 0; off >>= 1) s += __shfl_down(s, off, 64);
    if (l == 0) hn[k] = 0.5f * s;
}

// ---------------------------------------------------------------------------
// z [B,D,T] -> row-major fp16 split zh[N][D], zl[N][D] (transpose via LDS)
// ---------------------------------------------------------------------------
__global__ __launch_bounds__(256)
void prep_kernel(const float* __restrict__ z, f16* __restrict__ zh, f16* __restrict__ zl) {
    __shared__ float tile[64][129];
    const int tid = threadIdx.x;
    const int blk = blockIdx.x;              // 1024
    const int b   = blk >> 5;
    const int t0  = (blk & 31) * 64;
    const int n0  = b * T_ + t0;
    const float* zb = z + (size_t)b * D_ * T_ + t0;
#pragma unroll
    for (int it = 0; it < 8; it++) {
        int flat = it * 256 + tid;           // 128 d x 16 q
        int d = flat >> 4;
        int q = flat & 15;
        float4 zv = *(const float4*)(zb + (size_t)d * T_ + q * 4);
        tile[q * 4 + 0][d] = zv.x;
        tile[q * 4 + 1][d] = zv.y;
        tile[q * 4 + 2][d] = zv.z;
        tile[q * 4 + 3][d] = zv.w;
    }
    __syncthreads();
#pragma unroll
    for (int it = 0; it < 8; it++) {
        int r  = it * 8 + (tid >> 5);
        int d0 = (tid & 31) * 4;
        f16x4 hv, lv;
#pragma unroll
        for (int j = 0; j < 4; j++) {
            float v = tile[r][d0 + j];
            f16 hh = (f16)v;
            f16 ll = (f16)(v - (float)hh);
            if (j == 0) { hv.x = hh; lv.x = ll; }
            if (j == 1) { hv.y = hh; lv.y = ll; }
            if (j == 2) { hv.z = hh; lv.z = ll; }
            if (j == 3) { hv.w = hh; lv.w = ll; }
        }
        *(f16x4*)&zh[(size_t)(n0 + r) * D_ + d0] = hv;
        *(f16x4*)&zl[(size_t)(n0 + r) * D_ + d0] = lv;
    }
}

// ---------------------------------------------------------------------------
// MFMA distance-argmin, A-resident / B-streamed structure.
// dot(z,e) = zh.eh + zl.eh + zh.el  (split-fp16, error ~2^-22 |z.e|)
// Block = 64 rows x ALL 2048 codes (kb-loop inside). LDS:
//   AZH/AZL: 64 rows x 128 halves each (16 KB x2, staged ONCE, XOR-16 swizzle)
//   BS:      128 codes x 128 halves (32 KB, streamed per kb: eh tile, el tile)
//   = exactly 64 KB -> 2 blocks/CU (barrier-stall overlap).
// Per kb: eh-tile feeds BOTH zh.eh and zl.eh (64 MFMA/wave), el-tile feeds
// zh.el (32); per-lane running argmin in registers; ONE epilogue per block
// writes idx[n] and does the inverted-index count atomic (fused assign).
// ---------------------------------------------------------------------------
__global__ __launch_bounds__(256, 2)
void argmin_mfma(const f16* __restrict__ zh, const f16* __restrict__ zl,
                 const f16* __restrict__ eh, const f16* __restrict__ el,
                 const float* __restrict__ hn,
                 int* __restrict__ idx, int* __restrict__ cnt, int* __restrict__ pos) {
    __shared__ __align__(16) f16 AZH[64 * 128];   // 16 KB
    __shared__ __align__(16) f16 AZL[64 * 128];   // 16 KB
    __shared__ __align__(16) f16 BS[128 * 128];   // 32 KB

    const int tid = threadIdx.x;
    const int w   = tid >> 6;            // wave 0..3
    const int l   = tid & 63;
    const int wm  = w >> 1;              // row-half (32 rows)
    const int wn  = w & 1;               // code-half (64 codes of the 128-tile)
    const int n0  = blockIdx.x * 64;     // 1024 blocks
    const int c15 = l & 15;
    const int q   = l >> 4;

    // ---- stage A once: 4+4 load_lds16 per wave ----
#pragma unroll
    for (int i = 0; i < 4; i++) {
        int row = w * 16 + i * 4 + q;
        int g   = c15 ^ (row & 15);
        load_lds16(zh + (size_t)(n0 + row) * D_ + g * 8, &AZH[(w * 16 + i * 4) * 128]);
        load_lds16(zl + (size_t)(n0 + row) * D_ + g * 8, &AZL[(w * 16 + i * 4) * 128]);
    }

    float minv[2][4];
    int   mini[2][4];
#pragma unroll
    for (int mi = 0; mi < 2; mi++)
#pragma unroll
        for (int r = 0; r < 4; r++) { minv[mi][r] = FLT_MAX; mini[mi][r] = 0x7fffffff; }

    for (int kb = 0; kb < 16; kb++) {
        const int k0 = kb * 128;
        f32x4 acc[2][4];
#pragma unroll
        for (int mi = 0; mi < 2; mi++)
#pragma unroll
            for (int ni = 0; ni < 4; ni++) acc[mi][ni] = (f32x4){0.f, 0.f, 0.f, 0.f};

        // ---- eh tile: zh.eh + zl.eh ----
        __syncthreads();                 // BS reuse protection
#pragma unroll
        for (int i = 0; i < 8; i++) {
            int cl = w * 32 + i * 4 + q;
            int g  = c15 ^ (cl & 15);
            load_lds16(eh + (size_t)(k0 + cl) * D_ + g * 8, &BS[(w * 32 + i * 4) * 128]);
        }
        __syncthreads();                 // drain (also A on first iter)
#pragma unroll
        for (int s = 0; s < 4; s++) {
            const int gp = (s * 4 + q) ^ c15;
            f16x8 azh[2], azl[2], bf[4];
#pragma unroll
            for (int mi = 0; mi < 2; mi++) {
                int m = wm * 32 + mi * 16 + c15;
                azh[mi] = *(const f16x8*)&AZH[m * 128 + gp * 8];
                azl[mi] = *(const f16x8*)&AZL[m * 128 + gp * 8];
            }
#pragma unroll
            for (int ni = 0; ni < 4; ni++) {
                int n = wn * 64 + ni * 16 + c15;
                bf[ni] = *(const f16x8*)&BS[n * 128 + gp * 8];
            }
#pragma unroll
            for (int mi = 0; mi < 2; mi++)
#pragma unroll
                for (int ni = 0; ni < 4; ni++) {
                    acc[mi][ni] = __builtin_amdgcn_mfma_f32_16x16x32_f16(
                        azh[mi], bf[ni], acc[mi][ni], 0, 0, 0);
                    acc[mi][ni] = __builtin_amdgcn_mfma_f32_16x16x32_f16(
                        azl[mi], bf[ni], acc[mi][ni], 0, 0, 0);
                }
        }

        // ---- el tile: zh.el ----
        __syncthreads();
#pragma unroll
        for (int i = 0; i < 8; i++) {
            int cl = w * 32 + i * 4 + q;
            int g  = c15 ^ (cl & 15);
            load_lds16(el + (size_t)(k0 + cl) * D_ + g * 8, &BS[(w * 32 + i * 4) * 128]);
        }
        __syncthreads();
#pragma unroll
        for (int s = 0; s < 4; s++) {
            const int gp = (s * 4 + q) ^ c15;
            f16x8 azh[2], bf[4];
#pragma unroll
            for (int mi = 0; mi < 2; mi++) {
                int m = wm * 32 + mi * 16 + c15;
                azh[mi] = *(const f16x8*)&AZH[m * 128 + gp * 8];
            }
#pragma unroll
            for (int ni = 0; ni < 4; ni++) {
                int n = wn * 64 + ni * 16 + c15;
                bf[ni] = *(const f16x8*)&BS[n * 128 + gp * 8];
            }
#pragma unroll
            for (int mi = 0; mi < 2; mi++)
#pragma unroll
                for (int ni = 0; ni < 4; ni++)
                    acc[mi][ni] = __builtin_amdgcn_mfma_f32_16x16x32_f16(
                        azh[mi], bf[ni], acc[mi][ni], 0, 0, 0);
        }

        // ---- running argmin update (codes ascend: kb, ni ascending; strict <) ----
#pragma unroll
        for (int ni = 0; ni < 4; ni++) {
            int   k = k0 + wn * 64 + ni * 16 + c15;
            float h = hn[k];
#pragma unroll
            for (int mi = 0; mi < 2; mi++)
#pragma unroll
                for (int r = 0; r < 4; r++) {
                    float sc = h - acc[mi][ni][r];
                    if (sc < minv[mi][r]) { minv[mi][r] = sc; mini[mi][r] = k; }
                }
        }
    }

    // ---- single epilogue: cross-lane reduce, write idx + count atomic ----
    __syncthreads();                     // all MFMA/LDS reads done; alias A as red
    float* redv = (float*)AZH;           // [64][2]
    int*   redi = (int*)AZL;
#pragma unroll
    for (int mi = 0; mi < 2; mi++)
#pragma unroll
        for (int r = 0; r < 4; r++) {
            float bv = minv[mi][r];
            int   bi = mini[mi][r];
#pragma unroll
            for (int msk = 1; msk < 16; msk <<= 1) {
                float ov = __shfl_xor(bv, msk, 64);
                int   oi = __shfl_xor(bi, msk, 64);
                if (ov < bv || (ov == bv && oi < bi)) { bv = ov; bi = oi; }
            }
            if (c15 == 0) {
                int row = wm * 32 + mi * 16 + q * 4 + r;
                redv[row * 2 + wn] = bv;
                redi[row * 2 + wn] = bi;
            }
        }
    __syncthreads();
    if (tid < 64) {
        float v0 = redv[tid * 2 + 0]; int i0 = redi[tid * 2 + 0];
        float v1 = redv[tid * 2 + 1]; int i1 = redi[tid * 2 + 1];
        if (v1 < v0 || (v1 == v0 && i1 < i0)) { v0 = v1; i0 = i1; }
        int n = n0 + tid;
        idx[n] = i0;
        pos[n] = atomicAdd(&cnt[i0], 1);     // fused assign_kernel
    }
}

// ---------------------------------------------------------------------------
// Exclusive prefix sum over 2048 counts, single block of 256 threads.
// ---------------------------------------------------------------------------
__global__ __launch_bounds__(256)
void scan_kernel(const int* __restrict__ cnt, int* __restrict__ offs) {
    __shared__ int part[256];
    const int tid = threadIdx.x;
    int loc[8];
    int s = 0;
#pragma unroll
    for (int j = 0; j < 8; j++) { loc[j] = s; s += cnt[tid * 8 + j]; }
    part[tid] = s;
    __syncthreads();
    for (int off = 1; off < 256; off <<= 1) {
        int v = (tid >= off) ? part[tid - off] : 0;
        __syncthreads();
        part[tid] += v;
        __syncthreads();
    }
    int pre = (tid == 0) ? 0 : part[tid - 1];
#pragma unroll
    for (int j = 0; j < 8; j++) offs[tid * 8 + j] = pre + loc[j];
    if (tid == 255) offs[2048] = pre + s;    // == N
}

__global__ void bucket_kernel(const int* __restrict__ idx, const int* __restrict__ pos,
                              const int* __restrict__ offs, int* __restrict__ row_list) {
    int n = blockIdx.x * 256 + threadIdx.x;
    row_list[offs[idx[n]] + pos[n]] = n;
}

// ---------------------------------------------------------------------------
// STE output + loss: block = 64 t x 128 d tile of one b. Coalesced float4
// read/write of z/out0; codebook gather is L2-resident (emb = 1 MB).
// ---------------------------------------------------------------------------
__global__ __launch_bounds__(256)
void ste_kernel(const float* __restrict__ z, const float* __restrict__ emb,
                const int* __restrict__ idx, float* __restrict__ out0,
                float* __restrict__ s_loss) {
    __shared__ int   scode[64];
    __shared__ float red[256];
    const int tid = threadIdx.x;
    const int blk = blockIdx.x;              // 1024
    const int b   = blk >> 5;
    const int t0  = (blk & 31) * 64;
    const int n0  = b * T_ + t0;
    if (tid < 64) scode[tid] = idx[n0 + tid];
    __syncthreads();

    const float* zb = z    + (size_t)b * D_ * T_ + t0;
    float*       ob = out0 + (size_t)b * D_ * T_ + t0;
    float lsum = 0.0f;
#pragma unroll
    for (int it = 0; it < 8; it++) {
        int flat = it * 256 + tid;
        int d = flat >> 4;
        int q = flat & 15;
        float4 zv = *(const float4*)(zb + (size_t)d * T_ + q * 4);
        float zi[4] = {zv.x, zv.y, zv.z, zv.w};
        float ov[4];
#pragma unroll
        for (int j = 0; j < 4; j++) {
            int code = scode[q * 4 + j];
            float e  = emb[(size_t)code * D_ + d];
            float df = e - zi[j];            // z_vq - zf (one rounding)
            ov[j] = zi[j] + df;              // zf + (z_vq - zf), matches reference STE
            lsum += df * df;
        }
        float4 o4 = {ov[0], ov[1], ov[2], ov[3]};
        *(float4*)(ob + (size_t)d * T_ + q * 4) = o4;
    }

    red[tid] = lsum;
    __syncthreads();
    for (int s = 128; s > 0; s >>= 1) {
        if (tid < s) red[tid] += red[tid + s];
        __syncthreads();
    }
    if (tid == 0) atomicAdd(s_loss, red[0]);
}

// ---------------------------------------------------------------------------
// Per-code segment sum from zh+zl (hi+lo sum is exact fp32) — zero atomics,
// coalesced 256 B rows. Block per code, 4 row-groups x 32 lanes (d quads).
// ---------------------------------------------------------------------------
__global__ __launch_bounds__(128)
void sum_kernel(const f16* __restrict__ zh, const f16* __restrict__ zl,
                const int* __restrict__ row_list, const int* __restrict__ offs,
                float* __restrict__ sum_new, float* __restrict__ elem_new) {
    __shared__ float part[4][132];
    const int k  = blockIdx.x;
    const int g  = threadIdx.x >> 5;     // row group 0..3
    const int l  = threadIdx.x & 31;     // lane -> d quad
    const int lo = offs[k];
    const int hi = offs[k + 1];
    float4 acc = {0.0f, 0.0f, 0.0f, 0.0f};
    for (int i = lo + g; i < hi; i += 4) {
        int n = row_list[i];
        f16x4 hv = *(const f16x4*)&zh[(size_t)n * D_ + l * 4];
        f16x4 lv = *(const f16x4*)&zl[(size_t)n * D_ + l * 4];
        acc.x += (float)hv.x + (float)lv.x;
        acc.y += (float)hv.y + (float)lv.y;
        acc.z += (float)hv.z + (float)lv.z;
        acc.w += (float)hv.w + (float)lv.w;
    }
    part[g][l * 4 + 0] = acc.x;
    part[g][l * 4 + 1] = acc.y;
    part[g][l * 4 + 2] = acc.z;
    part[g][l * 4 + 3] = acc.w;
    __syncthreads();
    int d = threadIdx.x;
    sum_new[k * D_ + d] = part[0][d] + part[1][d] + part[2][d] + part[3][d];
    if (d == 0) elem_new[k] = (float)(hi - lo);
}

// ---------------------------------------------------------------------------
// EMA update, emb_new select, dk / entropy partial sums
// ---------------------------------------------------------------------------
__global__ __launch_bounds__(256)
void update_kernel(const float* __restrict__ emb, const float* __restrict__ emb_sum,
                   const float* __restrict__ emb_elem, const float* __restrict__ emb_rand,
                   const float* __restrict__ sum_new, const float* __restrict__ elem_new,
                   float* __restrict__ out_emb_new, float* __restrict__ out_emb_sum_n,
                   float* __restrict__ out_emb_elem_n,
                   float* __restrict__ s_ent, float* __restrict__ s_dk) {
    const float MU  = 0.99f;
    const float OMM = (float)(1.0 - 0.99);   // match JAX's fp64 1.0-0.99 -> fp32
    int gid = blockIdx.x * 256 + threadIdx.x;   // < K_*D_ = 262144
    int k = gid >> 7;
    int d = gid & 127;

    float sn = sum_new[gid];
    float es = emb_sum[gid];
    float en = elem_new[k];
    float ee = emb_elem[k];
    float esn = MU * es + OMM * sn;
    float een = MU * ee + OMM * en;
    out_emb_sum_n[gid] = esn;
    float enew = (een >= 1.0f) ? (esn / een) : emb_rand[gid];
    out_emb_new[gid] = enew;

    float df = enew - emb[gid];
    float v  = df * df;
    __shared__ float red[256];
    red[threadIdx.x] = v;
    __syncthreads();
    for (int s = 128; s > 0; s >>= 1) {
        if (threadIdx.x < s) red[threadIdx.x] += red[threadIdx.x + s];
        __syncthreads();
    }
    if (threadIdx.x == 0) atomicAdd(s_dk, red[0]);

    if (d == 0) {
        out_emb_elem_n[k] = een;
        float p = en * (1.0f / 65536.0f);   // sum(elem_new) == N exactly in fp32
        atomicAdd(s_ent, p * logf(p + 1e-8f));
    }
}

// ---------------------------------------------------------------------------
// Scalar finalization
// ---------------------------------------------------------------------------
__global__ void final_kernel(const float* __restrict__ s_loss, const float* __restrict__ s_ent,
                             const float* __restrict__ s_dk,
                             float* __restrict__ out_loss, float* __restrict__ out_ent,
                             float* __restrict__ out_dk) {
    out_loss[0] = s_loss[0];
    out_ent[0]  = expf(-s_ent[0]);
    out_dk[0]   = sqrtf(s_dk[0]) * (1.0f / 512.0f);   // sqrt(K*D) = 512
}

// ---------------------------------------------------------------------------
extern "C" void kernel_launch(void* const* d_in, const int* in_sizes, int n_in,
                              void* d_out, int out_size, void* d_ws, size_t ws_size,
                              hipStream_t stream) {
    (void)in_sizes; (void)n_in; (void)out_size; (void)ws_size;

    const float* z        = (const float*)d_in[0];   // [32,128,2048]
    const float* emb      = (const float*)d_in[1];   // [2048,128]
    const float* emb_sum  = (const float*)d_in[2];   // [2048,128]
    const float* emb_elem = (const float*)d_in[3];   // [2048]
    const float* emb_rand = (const float*)d_in[4];   // [2048,128]

    float* out = (float*)d_out;
    float* out0            = out;                            // z_vq_out  8388608
    float* out_loss        = out + 8388608;                  // scalar
    float* out_emb_new     = out + 8388609;                  // 262144
    float* out_emb_sum_n   = out + 8388609 + 262144;         // 262144
    float* out_emb_elem_n  = out + 8388609 + 524288;         // 2048
    float* out_ent         = out + 8388609 + 524288 + 2048;  // scalar
    float* out_dk          = out_ent + 1;                    // scalar

    float* ws = (float*)d_ws;                     // offsets in floats
    f16*   zh       = (f16*)(ws);                 // 8388608 halves (4194304 f)
    f16*   zl       = (f16*)(ws + 4194304);       // 8388608 halves
    int*   idx      = (int*)(ws + 8388608);       // 65536
    float* hn       = ws + 8454144;               // 2048
    f16*   eh       = (f16*)(ws + 8456192);       // 262144 halves (131072 f)
    f16*   el       = (f16*)(ws + 8587264);       // 262144 halves
    float* sum_new  = ws + 8718336;               // 262144
    float* elem_new = ws + 8980480;               // 2048
    int*   cnt      = (int*)(ws + 8982528);       // 2048
    float* scalars  = ws + 8984576;               // s_loss, s_ent, s_dk
    float* s_loss   = scalars;
    float* s_ent    = scalars + 1;
    float* s_dk     = scalars + 2;
    int*   pos      = (int*)(ws + 8984579);       // 65536
    int*   offs     = (int*)(ws + 9050115);       // 2049
    int*   row_list = (int*)(ws + 9052164);       // 65536
                                                  // end 9117700 f ~ 36.5 MB

    eprep_kernel<<<K_, 64, 0, stream>>>(emb, eh, el, hn, cnt, scalars);
    prep_kernel<<<B_ * (T_ / 64), 256, 0, stream>>>(z, zh, zl);
    argmin_mfma<<<N_ / 64, 256, 0, stream>>>(zh, zl, eh, el, hn, idx, cnt, pos);
    scan_kernel<<<1, 256, 0, stream>>>(cnt, offs);
    bucket_kernel<<<N_ / 256, 256, 0, stream>>>(idx, pos, offs, row_list);
    ste_kernel<<<B_ * (T_ / 64), 256, 0, stream>>>(z, emb, idx, out0, s_loss);
    sum_kernel<<<K_, 128, 0, stream>>>(zh, zl, row_list, offs, sum_new, elem_new);
    update_kernel<<<(K_ * D_) / 256, 256, 0, stream>>>(emb, emb_sum, emb_elem, emb_rand,
                                                       sum_new, elem_new,
                                                       out_emb_new, out_emb_sum_n,
                                                       out_emb_elem_n, s_ent, s_dk);
    final_kernel<<<1, 1, 0, stream>>>(s_loss, s_ent, s_dk, out_loss, out_ent, out_dk);
}

// Round 6
// 314.848 us; speedup vs baseline: 6.1158x; 1.4939x over previous
//
#include <hip/hip_runtime.h>
#include <float.h>
#include <math.h>

// Problem constants (from reference setup_inputs)
#define B_   32
#define D_   128
#define T_   2048
#define K_   2048
#define N_   (B_ * T_)      // 65536

typedef _Float16 f16;
typedef f16   f16x8 __attribute__((ext_vector_type(8)));
typedef f16   f16x4 __attribute__((ext_vector_type(4)));
typedef f16   f16x2 __attribute__((ext_vector_type(2)));
typedef float f32x4 __attribute__((ext_vector_type(4)));

// async global->LDS, 16 B per lane, LDS dst = wave-uniform base + lane*16
__device__ __forceinline__ void load_lds16(const void* g, void* l) {
    __builtin_amdgcn_global_load_lds(
        (const __attribute__((address_space(1))) unsigned int*)g,
        (__attribute__((address_space(3))) unsigned int*)l, 16, 0, 0);
}

// ---------------------------------------------------------------------------
// emb -> (eh, el) fp16 split + halfnorm. One wave per code.
// Also zeroes cnt[k], sum_new[k][:], and the 3 scalar accumulators.
// ---------------------------------------------------------------------------
__global__ void eprep_kernel(const float* __restrict__ emb, f16* __restrict__ eh,
                             f16* __restrict__ el, float* __restrict__ hn,
                             int* __restrict__ cnt, float* __restrict__ scalars,
                             float* __restrict__ sum_new) {
    int k = blockIdx.x;
    int l = threadIdx.x;            // 64
    if (l == 0) cnt[k] = 0;
    if (k == 0 && l < 3) scalars[l] = 0.0f;
    sum_new[(size_t)k * D_ + l]      = 0.0f;
    sum_new[(size_t)k * D_ + 64 + l] = 0.0f;
    float a = emb[(size_t)k * D_ + l];
    float b = emb[(size_t)k * D_ + 64 + l];
    f16 ah = (f16)a; f16 al = (f16)(a - (float)ah);
    f16 bh = (f16)b; f16 bl = (f16)(b - (float)bh);
    eh[(size_t)k * D_ + l]      = ah;
    eh[(size_t)k * D_ + 64 + l] = bh;
    el[(size_t)k * D_ + l]      = al;
    el[(size_t)k * D_ + 64 + l] = bl;
    float s = a * a + b * b;
#pragma unroll
    for (int off = 32; off > 0; off >>= 1) s += __shfl_down(s, off, 64);
    if (l == 0) hn[k] = 0.5f * s;
}

// ---------------------------------------------------------------------------
// z [B,D,T] -> row-major fp16 split zh[N][D], zl[N][D] (transpose via LDS)
// ---------------------------------------------------------------------------
__global__ __launch_bounds__(256)
void prep_kernel(const float* __restrict__ z, f16* __restrict__ zh, f16* __restrict__ zl) {
    __shared__ float tile[64][129];
    const int tid = threadIdx.x;
    const int blk = blockIdx.x;              // 1024
    const int b   = blk >> 5;
    const int t0  = (blk & 31) * 64;
    const int n0  = b * T_ + t0;
    const float* zb = z + (size_t)b * D_ * T_ + t0;
#pragma unroll
    for (int it = 0; it < 8; it++) {
        int flat = it * 256 + tid;           // 128 d x 16 q
        int d = flat >> 4;
        int q = flat & 15;
        float4 zv = *(const float4*)(zb + (size_t)d * T_ + q * 4);
        tile[q * 4 + 0][d] = zv.x;
        tile[q * 4 + 1][d] = zv.y;
        tile[q * 4 + 2][d] = zv.z;
        tile[q * 4 + 3][d] = zv.w;
    }
    __syncthreads();
#pragma unroll
    for (int it = 0; it < 8; it++) {
        int r  = it * 8 + (tid >> 5);
        int d0 = (tid & 31) * 4;
        f16x4 hv, lv;
#pragma unroll
        for (int j = 0; j < 4; j++) {
            float v = tile[r][d0 + j];
            f16 hh = (f16)v;
            f16 ll = (f16)(v - (float)hh);
            if (j == 0) { hv.x = hh; lv.x = ll; }
            if (j == 1) { hv.y = hh; lv.y = ll; }
            if (j == 2) { hv.z = hh; lv.z = ll; }
            if (j == 3) { hv.w = hh; lv.w = ll; }
        }
        *(f16x4*)&zh[(size_t)(n0 + r) * D_ + d0] = hv;
        *(f16x4*)&zl[(size_t)(n0 + r) * D_ + d0] = lv;
    }
}

// ---------------------------------------------------------------------------
// MFMA distance-argmin, A-resident / B-streamed structure.
// dot(z,e) = zh.eh + zl.eh + zh.el  (split-fp16, error ~2^-22 |z.e|)
// Block = 64 rows x ALL 2048 codes (kb-loop inside). LDS:
//   AZH/AZL: 64 rows x 128 halves each (16 KB x2, staged ONCE, XOR-16 swizzle)
//   BS:      128 codes x 128 halves (32 KB, streamed per kb: eh tile, el tile)
//   = exactly 64 KB -> 2 blocks/CU (barrier-stall overlap).
// Per kb: eh-tile feeds BOTH zh.eh and zl.eh (64 MFMA/wave), el-tile feeds
// zh.el (32); per-lane running argmin in registers; ONE epilogue per block
// writes idx[n] and does the inverted-index count atomic (fused assign).
// ---------------------------------------------------------------------------
__global__ __launch_bounds__(256, 2)
void argmin_mfma(const f16* __restrict__ zh, const f16* __restrict__ zl,
                 const f16* __restrict__ eh, const f16* __restrict__ el,
                 const float* __restrict__ hn,
                 int* __restrict__ idx, int* __restrict__ cnt, int* __restrict__ pos) {
    __shared__ __align__(16) f16 AZH[64 * 128];   // 16 KB
    __shared__ __align__(16) f16 AZL[64 * 128];   // 16 KB
    __shared__ __align__(16) f16 BS[128 * 128];   // 32 KB

    const int tid = threadIdx.x;
    const int w   = tid >> 6;            // wave 0..3
    const int l   = tid & 63;
    const int wm  = w >> 1;              // row-half (32 rows)
    const int wn  = w & 1;               // code-half (64 codes of the 128-tile)
    const int n0  = blockIdx.x * 64;     // 1024 blocks
    const int c15 = l & 15;
    const int q   = l >> 4;

    // ---- stage A once: 4+4 load_lds16 per wave ----
#pragma unroll
    for (int i = 0; i < 4; i++) {
        int row = w * 16 + i * 4 + q;
        int g   = c15 ^ (row & 15);
        load_lds16(zh + (size_t)(n0 + row) * D_ + g * 8, &AZH[(w * 16 + i * 4) * 128]);
        load_lds16(zl + (size_t)(n0 + row) * D_ + g * 8, &AZL[(w * 16 + i * 4) * 128]);
    }

    float minv[2][4];
    int   mini[2][4];
#pragma unroll
    for (int mi = 0; mi < 2; mi++)
#pragma unroll
        for (int r = 0; r < 4; r++) { minv[mi][r] = FLT_MAX; mini[mi][r] = 0x7fffffff; }

    for (int kb = 0; kb < 16; kb++) {
        const int k0 = kb * 128;
        f32x4 acc[2][4];
#pragma unroll
        for (int mi = 0; mi < 2; mi++)
#pragma unroll
            for (int ni = 0; ni < 4; ni++) acc[mi][ni] = (f32x4){0.f, 0.f, 0.f, 0.f};

        // ---- eh tile: zh.eh + zl.eh ----
        __syncthreads();                 // BS reuse protection
#pragma unroll
        for (int i = 0; i < 8; i++) {
            int cl = w * 32 + i * 4 + q;
            int g  = c15 ^ (cl & 15);
            load_lds16(eh + (size_t)(k0 + cl) * D_ + g * 8, &BS[(w * 32 + i * 4) * 128]);
        }
        __syncthreads();                 // drain (also A on first iter)
#pragma unroll
        for (int s = 0; s < 4; s++) {
            const int gp = (s * 4 + q) ^ c15;
            f16x8 azh[2], azl[2], bf[4];
#pragma unroll
            for (int mi = 0; mi < 2; mi++) {
                int m = wm * 32 + mi * 16 + c15;
                azh[mi] = *(const f16x8*)&AZH[m * 128 + gp * 8];
                azl[mi] = *(const f16x8*)&AZL[m * 128 + gp * 8];
            }
#pragma unroll
            for (int ni = 0; ni < 4; ni++) {
                int n = wn * 64 + ni * 16 + c15;
                bf[ni] = *(const f16x8*)&BS[n * 128 + gp * 8];
            }
#pragma unroll
            for (int mi = 0; mi < 2; mi++)
#pragma unroll
                for (int ni = 0; ni < 4; ni++) {
                    acc[mi][ni] = __builtin_amdgcn_mfma_f32_16x16x32_f16(
                        azh[mi], bf[ni], acc[mi][ni], 0, 0, 0);
                    acc[mi][ni] = __builtin_amdgcn_mfma_f32_16x16x32_f16(
                        azl[mi], bf[ni], acc[mi][ni], 0, 0, 0);
                }
        }

        // ---- el tile: zh.el ----
        __syncthreads();
#pragma unroll
        for (int i = 0; i < 8; i++) {
            int cl = w * 32 + i * 4 + q;
            int g  = c15 ^ (cl & 15);
            load_lds16(el + (size_t)(k0 + cl) * D_ + g * 8, &BS[(w * 32 + i * 4) * 128]);
        }
        __syncthreads();
#pragma unroll
        for (int s = 0; s < 4; s++) {
            const int gp = (s * 4 + q) ^ c15;
            f16x8 azh[2], bf[4];
#pragma unroll
            for (int mi = 0; mi < 2; mi++) {
                int m = wm * 32 + mi * 16 + c15;
                azh[mi] = *(const f16x8*)&AZH[m * 128 + gp * 8];
            }
#pragma unroll
            for (int ni = 0; ni < 4; ni++) {
                int n = wn * 64 + ni * 16 + c15;
                bf[ni] = *(const f16x8*)&BS[n * 128 + gp * 8];
            }
#pragma unroll
            for (int mi = 0; mi < 2; mi++)
#pragma unroll
                for (int ni = 0; ni < 4; ni++)
                    acc[mi][ni] = __builtin_amdgcn_mfma_f32_16x16x32_f16(
                        azh[mi], bf[ni], acc[mi][ni], 0, 0, 0);
        }

        // ---- running argmin update (codes ascend: kb, ni ascending; strict <) ----
#pragma unroll
        for (int ni = 0; ni < 4; ni++) {
            int   k = k0 + wn * 64 + ni * 16 + c15;
            float h = hn[k];
#pragma unroll
            for (int mi = 0; mi < 2; mi++)
#pragma unroll
                for (int r = 0; r < 4; r++) {
                    float sc = h - acc[mi][ni][r];
                    if (sc < minv[mi][r]) { minv[mi][r] = sc; mini[mi][r] = k; }
                }
        }
    }

    // ---- single epilogue: cross-lane reduce, write idx + count atomic ----
    __syncthreads();                     // all MFMA/LDS reads done; alias A as red
    float* redv = (float*)AZH;           // [64][2]
    int*   redi = (int*)AZL;
#pragma unroll
    for (int mi = 0; mi < 2; mi++)
#pragma unroll
        for (int r = 0; r < 4; r++) {
            float bv = minv[mi][r];
            int   bi = mini[mi][r];
#pragma unroll
            for (int msk = 1; msk < 16; msk <<= 1) {
                float ov = __shfl_xor(bv, msk, 64);
                int   oi = __shfl_xor(bi, msk, 64);
                if (ov < bv || (ov == bv && oi < bi)) { bv = ov; bi = oi; }
            }
            if (c15 == 0) {
                int row = wm * 32 + mi * 16 + q * 4 + r;
                redv[row * 2 + wn] = bv;
                redi[row * 2 + wn] = bi;
            }
        }
    __syncthreads();
    if (tid < 64) {
        float v0 = redv[tid * 2 + 0]; int i0 = redi[tid * 2 + 0];
        float v1 = redv[tid * 2 + 1]; int i1 = redi[tid * 2 + 1];
        if (v1 < v0 || (v1 == v0 && i1 < i0)) { v0 = v1; i0 = i1; }
        int n = n0 + tid;
        idx[n] = i0;
        pos[n] = atomicAdd(&cnt[i0], 1);     // fused assign_kernel
    }
}

// ---------------------------------------------------------------------------
// Exclusive prefix sum over 2048 counts, single block of 256 threads.
// ---------------------------------------------------------------------------
__global__ __launch_bounds__(256)
void scan_kernel(const int* __restrict__ cnt, int* __restrict__ offs) {
    __shared__ int part[256];
    const int tid = threadIdx.x;
    int loc[8];
    int s = 0;
#pragma unroll
    for (int j = 0; j < 8; j++) { loc[j] = s; s += cnt[tid * 8 + j]; }
    part[tid] = s;
    __syncthreads();
    for (int off = 1; off < 256; off <<= 1) {
        int v = (tid >= off) ? part[tid - off] : 0;
        __syncthreads();
        part[tid] += v;
        __syncthreads();
    }
    int pre = (tid == 0) ? 0 : part[tid - 1];
#pragma unroll
    for (int j = 0; j < 8; j++) offs[tid * 8 + j] = pre + loc[j];
    if (tid == 255) offs[2048] = pre + s;    // == N
}

__global__ void bucket_kernel(const int* __restrict__ idx, const int* __restrict__ pos,
                              const int* __restrict__ offs, int* __restrict__ row_list) {
    int n = blockIdx.x * 256 + threadIdx.x;
    row_list[offs[idx[n]] + pos[n]] = n;
}

// ---------------------------------------------------------------------------
// STE output + loss: block = 64 t x 128 d tile of one b. Coalesced float4
// read/write of z/out0; codebook gather is L2-resident (emb = 1 MB).
// ---------------------------------------------------------------------------
__global__ __launch_bounds__(256)
void ste_kernel(const float* __restrict__ z, const float* __restrict__ emb,
                const int* __restrict__ idx, float* __restrict__ out0,
                float* __restrict__ s_loss) {
    __shared__ int   scode[64];
    __shared__ float red[256];
    const int tid = threadIdx.x;
    const int blk = blockIdx.x;              // 1024
    const int b   = blk >> 5;
    const int t0  = (blk & 31) * 64;
    const int n0  = b * T_ + t0;
    if (tid < 64) scode[tid] = idx[n0 + tid];
    __syncthreads();

    const float* zb = z    + (size_t)b * D_ * T_ + t0;
    float*       ob = out0 + (size_t)b * D_ * T_ + t0;
    float lsum = 0.0f;
#pragma unroll
    for (int it = 0; it < 8; it++) {
        int flat = it * 256 + tid;
        int d = flat >> 4;
        int q = flat & 15;
        float4 zv = *(const float4*)(zb + (size_t)d * T_ + q * 4);
        float zi[4] = {zv.x, zv.y, zv.z, zv.w};
        float ov[4];
#pragma unroll
        for (int j = 0; j < 4; j++) {
            int code = scode[q * 4 + j];
            float e  = emb[(size_t)code * D_ + d];
            float df = e - zi[j];            // z_vq - zf (one rounding)
            ov[j] = zi[j] + df;              // zf + (z_vq - zf), matches reference STE
            lsum += df * df;
        }
        float4 o4 = {ov[0], ov[1], ov[2], ov[3]};
        *(float4*)(ob + (size_t)d * T_ + q * 4) = o4;
    }

    red[tid] = lsum;
    __syncthreads();
    for (int s = 128; s > 0; s >>= 1) {
        if (tid < s) red[tid] += red[tid + s];
        __syncthreads();
    }
    if (tid == 0) atomicAdd(s_loss, red[0]);
}

// ---------------------------------------------------------------------------
// Segment sum, balanced by ROW: wave per 64 consecutive row_list entries
// (row_list is code-sorted). Lane l owns d-pair {2l, 2l+1}; wave walks its
// 64 rows via shfl broadcast (wave-uniform, no divergence), flushing the
// running partial to sum_new with 2 fp32 atomics/lane at code boundaries.
// ~(1024 chunks + 2048 segments) flushes total; perfectly load-balanced.
// ---------------------------------------------------------------------------
__global__ __launch_bounds__(64)
void segsum_kernel(const f16* __restrict__ zh, const f16* __restrict__ zl,
                   const int* __restrict__ row_list, const int* __restrict__ idx,
                   float* __restrict__ sum_new) {
    const int l = threadIdx.x;           // 64
    const int base = blockIdx.x * 64;    // 1024 blocks
    int myrow  = row_list[base + l];
    int mycode = idx[myrow];
    float ax = 0.0f, ay = 0.0f;
    int cur = __shfl(mycode, 0, 64);
#pragma unroll 8
    for (int i = 0; i < 64; i++) {
        int r = __shfl(myrow, i, 64);
        int c = __shfl(mycode, i, 64);
        if (c != cur) {                  // wave-uniform branch
            atomicAdd(&sum_new[(size_t)cur * D_ + l * 2],     ax);
            atomicAdd(&sum_new[(size_t)cur * D_ + l * 2 + 1], ay);
            ax = 0.0f; ay = 0.0f; cur = c;
        }
        f16x2 hv = *(const f16x2*)&zh[(size_t)r * D_ + l * 2];
        f16x2 lv = *(const f16x2*)&zl[(size_t)r * D_ + l * 2];
        ax += (float)hv.x + (float)lv.x;
        ay += (float)hv.y + (float)lv.y;
    }
    atomicAdd(&sum_new[(size_t)cur * D_ + l * 2],     ax);
    atomicAdd(&sum_new[(size_t)cur * D_ + l * 2 + 1], ay);
}

// ---------------------------------------------------------------------------
// EMA update, emb_new select, dk / entropy partial sums.
// elem_new derived from offs (counts) — no separate buffer.
// ---------------------------------------------------------------------------
__global__ __launch_bounds__(256)
void update_kernel(const float* __restrict__ emb, const float* __restrict__ emb_sum,
                   const float* __restrict__ emb_elem, const float* __restrict__ emb_rand,
                   const float* __restrict__ sum_new, const int* __restrict__ offs,
                   float* __restrict__ out_emb_new, float* __restrict__ out_emb_sum_n,
                   float* __restrict__ out_emb_elem_n,
                   float* __restrict__ s_ent, float* __restrict__ s_dk) {
    const float MU  = 0.99f;
    const float OMM = (float)(1.0 - 0.99);   // match JAX's fp64 1.0-0.99 -> fp32
    int gid = blockIdx.x * 256 + threadIdx.x;   // < K_*D_ = 262144
    int k = gid >> 7;
    int d = gid & 127;

    float sn = sum_new[gid];
    float es = emb_sum[gid];
    float en = (float)(offs[k + 1] - offs[k]);
    float ee = emb_elem[k];
    float esn = MU * es + OMM * sn;
    float een = MU * ee + OMM * en;
    out_emb_sum_n[gid] = esn;
    float enew = (een >= 1.0f) ? (esn / een) : emb_rand[gid];
    out_emb_new[gid] = enew;

    float df = enew - emb[gid];
    float v  = df * df;
    __shared__ float red[256];
    red[threadIdx.x] = v;
    __syncthreads();
    for (int s = 128; s > 0; s >>= 1) {
        if (threadIdx.x < s) red[threadIdx.x] += red[threadIdx.x + s];
        __syncthreads();
    }
    if (threadIdx.x == 0) atomicAdd(s_dk, red[0]);

    if (d == 0) {
        out_emb_elem_n[k] = een;
        float p = en * (1.0f / 65536.0f);   // sum(elem_new) == N exactly in fp32
        atomicAdd(s_ent, p * logf(p + 1e-8f));
    }
}

// ---------------------------------------------------------------------------
// Scalar finalization
// ---------------------------------------------------------------------------
__global__ void final_kernel(const float* __restrict__ s_loss, const float* __restrict__ s_ent,
                             const float* __restrict__ s_dk,
                             float* __restrict__ out_loss, float* __restrict__ out_ent,
                             float* __restrict__ out_dk) {
    out_loss[0] = s_loss[0];
    out_ent[0]  = expf(-s_ent[0]);
    out_dk[0]   = sqrtf(s_dk[0]) * (1.0f / 512.0f);   // sqrt(K*D) = 512
}

// ---------------------------------------------------------------------------
extern "C" void kernel_launch(void* const* d_in, const int* in_sizes, int n_in,
                              void* d_out, int out_size, void* d_ws, size_t ws_size,
                              hipStream_t stream) {
    (void)in_sizes; (void)n_in; (void)out_size; (void)ws_size;

    const float* z        = (const float*)d_in[0];   // [32,128,2048]
    const float* emb      = (const float*)d_in[1];   // [2048,128]
    const float* emb_sum  = (const float*)d_in[2];   // [2048,128]
    const float* emb_elem = (const float*)d_in[3];   // [2048]
    const float* emb_rand = (const float*)d_in[4];   // [2048,128]

    float* out = (float*)d_out;
    float* out0            = out;                            // z_vq_out  8388608
    float* out_loss        = out + 8388608;                  // scalar
    float* out_emb_new     = out + 8388609;                  // 262144
    float* out_emb_sum_n   = out + 8388609 + 262144;         // 262144
    float* out_emb_elem_n  = out + 8388609 + 524288;         // 2048
    float* out_ent         = out + 8388609 + 524288 + 2048;  // scalar
    float* out_dk          = out_ent + 1;                    // scalar

    float* ws = (float*)d_ws;                     // offsets in floats
    f16*   zh       = (f16*)(ws);                 // 8388608 halves (4194304 f)
    f16*   zl       = (f16*)(ws + 4194304);       // 8388608 halves
    int*   idx      = (int*)(ws + 8388608);       // 65536
    float* hn       = ws + 8454144;               // 2048
    f16*   eh       = (f16*)(ws + 8456192);       // 262144 halves (131072 f)
    f16*   el       = (f16*)(ws + 8587264);       // 262144 halves
    float* sum_new  = ws + 8718336;               // 262144
    int*   cnt      = (int*)(ws + 8980480);       // 2048
    float* scalars  = ws + 8982528;               // s_loss, s_ent, s_dk
    float* s_loss   = scalars;
    float* s_ent    = scalars + 1;
    float* s_dk     = scalars + 2;
    int*   pos      = (int*)(ws + 8982531);       // 65536
    int*   offs     = (int*)(ws + 9048067);       // 2049
    int*   row_list = (int*)(ws + 9050116);       // 65536
                                                  // end 9115652 f ~ 36.5 MB

    eprep_kernel<<<K_, 64, 0, stream>>>(emb, eh, el, hn, cnt, scalars, sum_new);
    prep_kernel<<<B_ * (T_ / 64), 256, 0, stream>>>(z, zh, zl);
    argmin_mfma<<<N_ / 64, 256, 0, stream>>>(zh, zl, eh, el, hn, idx, cnt, pos);
    scan_kernel<<<1, 256, 0, stream>>>(cnt, offs);
    bucket_kernel<<<N_ / 256, 256, 0, stream>>>(idx, pos, offs, row_list);
    ste_kernel<<<B_ * (T_ / 64), 256, 0, stream>>>(z, emb, idx, out0, s_loss);
    segsum_kernel<<<N_ / 64, 64, 0, stream>>>(zh, zl, row_list, idx, sum_new);
    update_kernel<<<(K_ * D_) / 256, 256, 0, stream>>>(emb, emb_sum, emb_elem, emb_rand,
                                                       sum_new, offs,
                                                       out_emb_new, out_emb_sum_n,
                                                       out_emb_elem_n, s_ent, s_dk);
    final_kernel<<<1, 1, 0, stream>>>(s_loss, s_ent, s_dk, out_loss, out_ent, out_dk);
}